// Round 3
// baseline (279.118 us; speedup 1.0000x reference)
//
#include <hip/hip_runtime.h>
#include <math.h>

#define NCELLS 2097152  // 128^3

// ================= FFT core: Stockham radix-2, lines of 128 in LDS =================
// tw[Ns+k] = exp(-i*pi*k/Ns) for Ns=1..64 (indices 1..127). Computed per block.
__device__ __forceinline__ void init_tw(float2* tw, int tid) {
  if (tid >= 1 && tid < 128) {
    int Ns = 1 << (31 - __clz(tid));
    int k = tid - Ns;
    float ang = -3.14159265358979323846f * (float)k / (float)Ns;
    float s, c;
    sincosf(ang, &s, &c);
    tw[tid] = make_float2(c, s);
  }
}

// L lines of 128 complex, ping-pong in sc[2][L][129]. NT = block threads.
// Caller must __syncthreads() after filling sc[0]. Returns final buffer idx.
template<int DIR, int L, int NT>
__device__ __forceinline__ int fft_lines(float2 (*sc)[L][129], const float2* tw, int tid) {
  int cur = 0;
  #pragma unroll
  for (int s = 0; s < 7; s++) {
    const int Ns = 1 << s;
    for (int t = tid; t < L * 64; t += NT) {
      int l = t >> 6, j = t & 63;
      float2 a = sc[cur][l][j];
      float2 b = sc[cur][l][j + 64];
      int k = j & (Ns - 1);
      float2 w = tw[Ns + k];
      float wy = (DIR < 0) ? w.y : -w.y;  // inverse = conjugate twiddle
      float2 wb = make_float2(w.x * b.x - wy * b.y, w.x * b.y + wy * b.x);
      int ob = ((j >> s) << (s + 1)) + k;
      sc[cur ^ 1][l][ob]      = make_float2(a.x + wb.x, a.y + wb.y);
      sc[cur ^ 1][l][ob + Ns] = make_float2(a.x - wb.x, a.y - wb.y);
    }
    cur ^= 1;
    __syncthreads();
  }
  return cur;
}

// ================= raster path: bin by (x,y) column =================
__global__ __launch_bounds__(256) void hist_kernel(const float* __restrict__ pts,
                                                   int* __restrict__ counts, int npts) {
  int i = blockIdx.x * 256 + threadIdx.x;
  if (i >= npts) return;
  int lx = ((int)floorf(pts[3*i+0] * 128.0f)) & 127;
  int ly = ((int)floorf(pts[3*i+1] * 128.0f)) & 127;
  atomicAdd(counts + ((lx << 7) + ly), 1);
}

__global__ __launch_bounds__(1024) void scan16k(const int* __restrict__ counts,
                                                int* __restrict__ off,
                                                int* __restrict__ cur) {
  __shared__ int part[1024];
  int t = threadIdx.x;
  int local[16]; int s = 0;
  #pragma unroll
  for (int k = 0; k < 16; k++) { local[k] = s; s += counts[t * 16 + k]; }
  part[t] = s;
  __syncthreads();
  for (int d = 1; d < 1024; d <<= 1) {
    int v = (t >= d) ? part[t - d] : 0;
    __syncthreads();
    part[t] += v;
    __syncthreads();
  }
  int base = (t == 0) ? 0 : part[t - 1];
  #pragma unroll
  for (int k = 0; k < 16; k++) {
    int o = base + local[k];
    off[t * 16 + k] = o;
    cur[t * 16 + k] = o;
  }
  if (t == 1023) off[16384] = part[1023];
}

__global__ __launch_bounds__(256) void scatter_kernel(const float* __restrict__ pts,
                                                      const float* __restrict__ nrm,
                                                      int* __restrict__ cur,
                                                      float4* __restrict__ sorted, int npts) {
  int i = blockIdx.x * 256 + threadIdx.x;
  if (i >= npts) return;
  float px = pts[3*i+0], py = pts[3*i+1], pz = pts[3*i+2];
  int lx = ((int)floorf(px * 128.0f)) & 127;
  int ly = ((int)floorf(py * 128.0f)) & 127;
  int slot = atomicAdd(cur + ((lx << 7) + ly), 1);
  sorted[2*slot]   = make_float4(px, py, pz, 0.0f);
  sorted[2*slot+1] = make_float4(nrm[3*i+0], nrm[3*i+1], nrm[3*i+2], 0.0f);
}

__global__ __launch_bounds__(128) void raster_cols(const float4* __restrict__ sorted,
                                                   const int* __restrict__ off,
                                                   float* __restrict__ vr) {
  int col = blockIdx.x;            // x*128 + y
  int x = col >> 7, y = col & 127;
  __shared__ float acc[3][128];
  for (int t = threadIdx.x; t < 384; t += 128) ((float*)acc)[t] = 0.0f;
  __syncthreads();
  #pragma unroll
  for (int q = 0; q < 4; q++) {
    int bx = (q & 2) ? x : (x + 127) & 127;
    int by = (q & 1) ? y : (y + 127) & 127;
    int b = (bx << 7) + by;
    int s = off[b], e = off[b + 1];
    for (int p = s + threadIdx.x; p < e; p += 128) {
      float4 P  = sorted[2*p];
      float4 Nm = sorted[2*p+1];
      float tx = P.x * 128.0f, ty = P.y * 128.0f, tz = P.z * 128.0f;
      float fx = tx - floorf(tx), fy = ty - floorf(ty), fz = tz - floorf(tz);
      int lz = ((int)floorf(tz)) & 127;
      int z1 = (lz + 1) & 127;
      float wx = (q & 2) ? (1.0f - fx) : fx;
      float wy = (q & 1) ? (1.0f - fy) : fy;
      float w0 = wx * wy * (1.0f - fz), w1 = wx * wy * fz;
      atomicAdd(&acc[0][lz], w0 * Nm.x); atomicAdd(&acc[0][z1], w1 * Nm.x);
      atomicAdd(&acc[1][lz], w0 * Nm.y); atomicAdd(&acc[1][z1], w1 * Nm.y);
      atomicAdd(&acc[2][lz], w0 * Nm.z); atomicAdd(&acc[2][z1], w1 * Nm.z);
    }
  }
  __syncthreads();
  int base = col << 7;
  for (int t = threadIdx.x; t < 384; t += 128) {
    int c = t >> 7, z = t & 127;
    vr[c * NCELLS + base + z] = acc[c][z];
  }
}

// ================= pass A: forward z-FFT + transpose =================
// g=0: Zp = FFTz(v0 + i*v1); g=1: Z2 = FFTz(v2). Output layout [w][x][y].
__global__ __launch_bounds__(256) void pass_a(const float* __restrict__ vr,
                                              float2* __restrict__ Zp,
                                              float2* __restrict__ Z2) {
  __shared__ float2 sc[2][16][129];
  __shared__ float2 tw[128];
  int tid = threadIdx.x;
  init_tw(tw, tid);
  int x = blockIdx.x >> 3, y0 = (blockIdx.x & 7) << 4;
  int g = blockIdx.y;
  const float* s0 = vr + (g ? 2 * NCELLS : 0);
  const float* s1 = vr + NCELLS;
  for (int e = tid; e < 2048; e += 256) {
    int l = e >> 7, z = e & 127;
    int gi = (x * 128 + y0 + l) * 128 + z;
    float re = s0[gi];
    float im = g ? 0.0f : s1[gi];
    sc[0][l][z] = make_float2(re, im);
  }
  __syncthreads();
  int cur = fft_lines<-1, 16, 256>(sc, tw, tid);
  float2* D = g ? Z2 : Zp;
  for (int e = tid; e < 2048; e += 256) {
    int w = e >> 4, l = e & 15;
    D[(w * 128 + x) * 128 + y0 + l] = sc[cur][l][w];
  }
}

// ================= pass B: forward 2D xy-FFT per z-frequency slice =================
// One block per slice per grid (256 blocks). Whole 128x128 slice in LDS.
__global__ __launch_bounds__(512) void pass_b(float2* __restrict__ Zp,
                                              float2* __restrict__ Z2) {
  __shared__ float2 M[128][129];
  __shared__ float2 sc[2][8][129];
  __shared__ float2 tw[128];
  int tid = threadIdx.x;
  init_tw(tw, tid);
  float2* base = ((blockIdx.x >> 7) ? Z2 : Zp) + (blockIdx.x & 127) * 16384;

  // ---- y-FFTs (rows are y-contiguous), 16 batches of 8 rows, 1-deep prefetch ----
  float2 pre[2], nxt[2];
  #pragma unroll
  for (int q = 0; q < 2; q++) {
    int e = tid + q * 512;                        // e in [0,1024): l=e>>7, y=e&127
    pre[q] = base[(e >> 7) * 128 + (e & 127)];
  }
  for (int b = 0; b < 16; b++) {
    #pragma unroll
    for (int q = 0; q < 2; q++) {
      int e = tid + q * 512;
      sc[0][e >> 7][e & 127] = pre[q];
    }
    if (b + 1 < 16) {
      #pragma unroll
      for (int q = 0; q < 2; q++) {
        int e = tid + q * 512;
        nxt[q] = base[(b + 1) * 1024 + (e >> 7) * 128 + (e & 127)];
      }
    }
    __syncthreads();
    int cur = fft_lines<-1, 8, 512>(sc, tw, tid);
    #pragma unroll
    for (int q = 0; q < 2; q++) {
      int e = tid + q * 512;
      M[b * 8 + (e >> 7)][e & 127] = sc[cur][e >> 7][e & 127];
    }
    __syncthreads();
    #pragma unroll
    for (int q = 0; q < 2; q++) pre[q] = nxt[q];   // waitcnt lands here, after FFT
  }

  // ---- x-FFTs (columns, stride 129: 2-way bank alias only) ----
  for (int b = 0; b < 16; b++) {
    #pragma unroll
    for (int q = 0; q < 2; q++) {
      int e = tid + q * 512;                      // l=e>>7, x=e&127
      sc[0][e >> 7][e & 127] = M[e & 127][b * 8 + (e >> 7)];
    }
    __syncthreads();
    int cur = fft_lines<-1, 8, 512>(sc, tw, tid);
    #pragma unroll
    for (int q = 0; q < 2; q++) {
      int e = tid + q * 512;
      M[e & 127][b * 8 + (e >> 7)] = sc[cur][e >> 7][e & 127];
    }
    __syncthreads();
  }

  for (int e = tid; e < 16384; e += 512)
    base[e] = M[e >> 7][e & 127];
}

// ================= pass CD: spectral solve + Hermitian unpack + inverse 2D xy =================
// One block per slice w (128 blocks). Writes chi_z in-place into Z2.
__global__ __launch_bounds__(512) void pass_cd(const float2* __restrict__ Zp,
                                               float2* __restrict__ Z2) {
  __shared__ float2 M[128][129];
  __shared__ float2 sc[2][8][129];
  __shared__ float2 tw[128];
  int tid = threadIdx.x;
  init_tw(tw, tid);
  int w = blockIdx.x;
  int wm = (128 - w) & 127;
  float fz = (float)(w < 64 ? w : w - 128);

  for (int e = tid; e < 16384; e += 512) {
    int kx = e >> 7, ky = e & 127;
    int kxm = (128 - kx) & 127, kym = (128 - ky) & 127;
    float2 A  = Zp[w * 16384 + e];
    float2 Bm = Zp[wm * 16384 + kxm * 128 + kym];
    float2 v2 = Z2[w * 16384 + e];                 // v2 real -> Z2 is its true spectrum
    float2 v0 = make_float2(0.5f * (A.x + Bm.x), 0.5f * (A.y - Bm.y));
    float2 v1 = make_float2(0.5f * (A.y + Bm.y), 0.5f * (Bm.x - A.x));
    float fx = (float)(kx < 64 ? kx : kx - 128);
    float fy = (float)(ky < 64 ? ky : ky - 128);
    float u2 = fx * fx + fy * fy + fz * fz;
    float g = __expf(-0.0030517578125f * u2);      // -2*(5/128)^2*u2
    float coef = g / (6.28318530717958648f * (u2 + 1e-6f)) * (1.0f / 2097152.0f);
    float dre = fx * v0.x + fy * v1.x + fz * v2.x;
    float dim = fx * v0.y + fy * v1.y + fz * v2.y;
    M[kx][ky] = make_float2(coef * dim, -coef * dre);  // (-i)*(a+bi) = (b,-a)
  }
  __syncthreads();

  // inverse y (rows)
  for (int b = 0; b < 16; b++) {
    #pragma unroll
    for (int q = 0; q < 2; q++) {
      int e = tid + q * 512;
      sc[0][e >> 7][e & 127] = M[b * 8 + (e >> 7)][e & 127];
    }
    __syncthreads();
    int cur = fft_lines<1, 8, 512>(sc, tw, tid);
    #pragma unroll
    for (int q = 0; q < 2; q++) {
      int e = tid + q * 512;
      M[b * 8 + (e >> 7)][e & 127] = sc[cur][e >> 7][e & 127];
    }
    __syncthreads();
  }
  // inverse x (columns)
  for (int b = 0; b < 16; b++) {
    #pragma unroll
    for (int q = 0; q < 2; q++) {
      int e = tid + q * 512;
      sc[0][e >> 7][e & 127] = M[e & 127][b * 8 + (e >> 7)];
    }
    __syncthreads();
    int cur = fft_lines<1, 8, 512>(sc, tw, tid);
    #pragma unroll
    for (int q = 0; q < 2; q++) {
      int e = tid + q * 512;
      M[e & 127][b * 8 + (e >> 7)] = sc[cur][e >> 7][e & 127];
    }
    __syncthreads();
  }

  for (int e = tid; e < 16384; e += 512)
    Z2[w * 16384 + e] = M[e >> 7][e & 127];
}

// ================= pass E: inverse z-FFT + un-transpose + real write =================
__global__ __launch_bounds__(256) void pass_e(const float2* __restrict__ Cz,
                                              float* __restrict__ chi) {
  __shared__ float2 sc[2][16][129];
  __shared__ float2 tw[128];
  int tid = threadIdx.x;
  init_tw(tw, tid);
  int x = blockIdx.x >> 3, y0 = (blockIdx.x & 7) << 4;
  for (int e = tid; e < 2048; e += 256) {
    int w = e >> 4, l = e & 15;
    sc[0][l][w] = Cz[(w * 128 + x) * 128 + y0 + l];
  }
  __syncthreads();
  int cur = fft_lines<1, 16, 256>(sc, tw, tid);
  for (int e = tid; e < 2048; e += 256) {
    int l = e >> 7, z = e & 127;
    chi[(x * 128 + y0 + l) * 128 + z] = sc[cur][l][z].x;
  }
}

// ================= interpolation + mean, finalize =================
__global__ __launch_bounds__(256) void interp_mean(const float* __restrict__ pts,
                                                   const float* __restrict__ chi,
                                                   float* __restrict__ sum, int npts) {
  int i = blockIdx.x * 256 + threadIdx.x;
  float v = 0.0f;
  if (i < npts) {
    float tx = pts[3*i+0] * 128.0f, ty = pts[3*i+1] * 128.0f, tz = pts[3*i+2] * 128.0f;
    int lx = (int)floorf(tx), ly = (int)floorf(ty), lz = (int)floorf(tz);
    float fx = tx - (float)lx, fy = ty - (float)ly, fz = tz - (float)lz;
    lx &= 127; ly &= 127; lz &= 127;
    int hx = (lx + 1) & 127, hy = (ly + 1) & 127, hz = (lz + 1) & 127;
    #pragma unroll
    for (int c = 0; c < 8; c++) {
      int ix = (c & 4) ? hx : lx; float wx = (c & 4) ? fx : 1.0f - fx;
      int iy = (c & 2) ? hy : ly; float wy = (c & 2) ? fy : 1.0f - fy;
      int iz = (c & 1) ? hz : lz; float wz = (c & 1) ? fz : 1.0f - fz;
      v += wx * wy * wz * chi[(ix << 14) + (iy << 7) + iz];
    }
  }
  #pragma unroll
  for (int off = 32; off > 0; off >>= 1) v += __shfl_down(v, off, 64);
  if ((threadIdx.x & 63) == 0) atomicAdd(sum, v);
}

__global__ __launch_bounds__(256) void finalize(const float* __restrict__ chi,
                                                const float* __restrict__ sum,
                                                float* __restrict__ out, int npts) {
  int i = blockIdx.x * 256 + threadIdx.x;
  float mean = sum[0] / (float)npts;
  float chi0 = chi[0] - mean;
  float scale = 0.5f / fabsf(chi0);
  out[i] = scale * (chi[i] - mean);
}

// ================= launch =================
extern "C" void kernel_launch(void* const* d_in, const int* in_sizes, int n_in,
                              void* d_out, int out_size, void* d_ws, size_t ws_size,
                              hipStream_t stream) {
  const float* pts = (const float*)d_in[0];
  const float* nrm = (const float*)d_in[1];
  float* out = (float*)d_out;
  int npts = in_sizes[0] / 3;  // 131072

  char* p = (char*)d_ws;
  float2* Zp     = (float2*)p;  p += (size_t)NCELLS * sizeof(float2);     // 16.8 MB
  float2* Z2     = (float2*)p;  p += (size_t)NCELLS * sizeof(float2);     // 16.8 MB
  float*  vr     = (float*)p;   p += 3ull * NCELLS * sizeof(float);       // 25.2 MB
  float4* sorted = (float4*)p;  p += 2ull * 131072 * sizeof(float4);      // 4.2 MB
  float*  chi    = (float*)p;   p += (size_t)NCELLS * sizeof(float);      // 8.4 MB
  int*    counts = (int*)p;     p += 16384 * sizeof(int);
  float*  sum    = (float*)p;   p += sizeof(float);
  int*    off    = (int*)p;     p += 16385 * sizeof(int);
  int*    cur    = (int*)p;

  hipMemsetAsync(counts, 0, 16384 * sizeof(int) + sizeof(float), stream);  // counts + sum

  hist_kernel<<<(npts + 255) / 256, 256, 0, stream>>>(pts, counts, npts);
  scan16k<<<1, 1024, 0, stream>>>(counts, off, cur);
  scatter_kernel<<<(npts + 255) / 256, 256, 0, stream>>>(pts, nrm, cur, sorted, npts);
  raster_cols<<<16384, 128, 0, stream>>>(sorted, off, vr);

  pass_a<<<dim3(1024, 2), 256, 0, stream>>>(vr, Zp, Z2);
  pass_b<<<256, 512, 0, stream>>>(Zp, Z2);
  pass_cd<<<128, 512, 0, stream>>>(Zp, Z2);
  pass_e<<<1024, 256, 0, stream>>>(Z2, chi);

  interp_mean<<<(npts + 255) / 256, 256, 0, stream>>>(pts, chi, sum, npts);
  finalize<<<NCELLS / 256, 256, 0, stream>>>(chi, sum, out, npts);
}

// Round 4
// 231.040 us; speedup vs baseline: 1.2081x; 1.2081x over previous
//
#include <hip/hip_runtime.h>
#include <math.h>

#define NCELLS 2097152  // 128^3

// ================= complex helpers =================
__device__ __forceinline__ float2 cadd(float2 a, float2 b){ return make_float2(a.x+b.x, a.y+b.y); }
__device__ __forceinline__ float2 csub(float2 a, float2 b){ return make_float2(a.x-b.x, a.y-b.y); }
// multiply by w (DIR<0, forward) or conj(w) (DIR>0, inverse); table stores exp(-i theta)
template<int DIR>
__device__ __forceinline__ float2 ctw(float2 b, float2 w) {
  if (DIR < 0) return make_float2(b.x*w.x - b.y*w.y, b.x*w.y + b.y*w.x);
  else         return make_float2(b.x*w.x + b.y*w.y, b.y*w.x - b.x*w.y);
}

// tw[Ns+k] = exp(-i*pi*k/Ns), indices 1..127
__device__ __forceinline__ void init_tw(float2* tw, int tid) {
  if (tid >= 1 && tid < 128) {
    int Ns = 1 << (31 - __clz(tid));
    int k = tid - Ns;
    float ang = -3.14159265358979323846f * (float)k / (float)Ns;
    float s, c;
    sincosf(ang, &s, &c);
    tw[tid] = make_float2(c, s);
  }
}

// ===== mixed-radix Stockham FFT of 16 lines of 128, in-place at (base, line-stride ls,
// elem-stride es), scratch S[16][128], 512 threads, radix 4/4/4/2, natural->natural order.
template<int DIR>
__device__ __forceinline__ void fft16(float2* __restrict__ base, int ls, int es,
                                      float2 (*__restrict__ S)[128],
                                      const float2* __restrict__ tw, int tid) {
  int l = tid >> 5, j = tid & 31;
  float2* B = base + l * ls;
  { // stage 0: radix-4, Ns=1, B -> S (twiddles = 1)
    float2 a = B[j*es], b = B[(j+32)*es], c = B[(j+64)*es], d = B[(j+96)*es];
    float2 t0 = cadd(a,c), t1 = csub(a,c), t2 = cadd(b,d), t3s = csub(b,d);
    float2 t3 = (DIR<0) ? make_float2(t3s.y,-t3s.x) : make_float2(-t3s.y,t3s.x);
    int o = j << 2;
    S[l][o] = cadd(t0,t2); S[l][o+1] = cadd(t1,t3);
    S[l][o+2] = csub(t0,t2); S[l][o+3] = csub(t1,t3);
  }
  __syncthreads();
  { // stage 1: radix-4, Ns=4, S -> B
    int k = j & 3;
    float2 a = S[l][j], b = S[l][j+32], c = S[l][j+64], d = S[l][j+96];
    float2 w1 = tw[8+k], w2 = tw[4+k];
    float2 w3 = make_float2(w1.x*w2.x - w1.y*w2.y, w1.x*w2.y + w1.y*w2.x);
    b = ctw<DIR>(b,w1); c = ctw<DIR>(c,w2); d = ctw<DIR>(d,w3);
    float2 t0 = cadd(a,c), t1 = csub(a,c), t2 = cadd(b,d), t3s = csub(b,d);
    float2 t3 = (DIR<0) ? make_float2(t3s.y,-t3s.x) : make_float2(-t3s.y,t3s.x);
    int o = ((j>>2)<<4) + k;
    B[o*es] = cadd(t0,t2); B[(o+4)*es] = cadd(t1,t3);
    B[(o+8)*es] = csub(t0,t2); B[(o+12)*es] = csub(t1,t3);
  }
  __syncthreads();
  { // stage 2: radix-4, Ns=16, B -> S
    int k = j & 15;
    float2 a = B[j*es], b = B[(j+32)*es], c = B[(j+64)*es], d = B[(j+96)*es];
    float2 w1 = tw[32+k], w2 = tw[16+k];
    float2 w3 = make_float2(w1.x*w2.x - w1.y*w2.y, w1.x*w2.y + w1.y*w2.x);
    b = ctw<DIR>(b,w1); c = ctw<DIR>(c,w2); d = ctw<DIR>(d,w3);
    float2 t0 = cadd(a,c), t1 = csub(a,c), t2 = cadd(b,d), t3s = csub(b,d);
    float2 t3 = (DIR<0) ? make_float2(t3s.y,-t3s.x) : make_float2(-t3s.y,t3s.x);
    int o = ((j>>4)<<6) + k;
    S[l][o] = cadd(t0,t2); S[l][o+16] = cadd(t1,t3);
    S[l][o+32] = csub(t0,t2); S[l][o+48] = csub(t1,t3);
  }
  __syncthreads();
  // stage 3: radix-2, Ns=64, S -> B (1024 tasks, 2 per thread)
  #pragma unroll
  for (int q = 0; q < 2; q++) {
    int t = tid + q*512;
    int l2 = t >> 6, j2 = t & 63;
    float2 a = S[l2][j2], b = S[l2][j2+64];
    b = ctw<DIR>(b, tw[64+j2]);
    float2* D = base + l2*ls;
    D[j2*es] = cadd(a,b); D[(j2+64)*es] = csub(a,b);
  }
  __syncthreads();
}

// ================= raster path: bin by (x,y) column =================
__global__ __launch_bounds__(256) void hist_kernel(const float* __restrict__ pts,
                                                   int* __restrict__ counts, int npts) {
  int i = blockIdx.x * 256 + threadIdx.x;
  if (i >= npts) return;
  int lx = ((int)floorf(pts[3*i+0] * 128.0f)) & 127;
  int ly = ((int)floorf(pts[3*i+1] * 128.0f)) & 127;
  atomicAdd(counts + ((lx << 7) + ly), 1);
}

__global__ __launch_bounds__(1024) void scan16k(const int* __restrict__ counts,
                                                int* __restrict__ off,
                                                int* __restrict__ cur) {
  __shared__ int part[1024];
  int t = threadIdx.x;
  int local[16]; int s = 0;
  #pragma unroll
  for (int k = 0; k < 16; k++) { local[k] = s; s += counts[t * 16 + k]; }
  part[t] = s;
  __syncthreads();
  for (int d = 1; d < 1024; d <<= 1) {
    int v = (t >= d) ? part[t - d] : 0;
    __syncthreads();
    part[t] += v;
    __syncthreads();
  }
  int base = (t == 0) ? 0 : part[t - 1];
  #pragma unroll
  for (int k = 0; k < 16; k++) {
    int o = base + local[k];
    off[t * 16 + k] = o;
    cur[t * 16 + k] = o;
  }
  if (t == 1023) off[16384] = part[1023];
}

__global__ __launch_bounds__(256) void scatter_kernel(const float* __restrict__ pts,
                                                      const float* __restrict__ nrm,
                                                      int* __restrict__ cur,
                                                      float4* __restrict__ sorted, int npts) {
  int i = blockIdx.x * 256 + threadIdx.x;
  if (i >= npts) return;
  float px = pts[3*i+0], py = pts[3*i+1], pz = pts[3*i+2];
  int lx = ((int)floorf(px * 128.0f)) & 127;
  int ly = ((int)floorf(py * 128.0f)) & 127;
  int slot = atomicAdd(cur + ((lx << 7) + ly), 1);
  sorted[2*slot]   = make_float4(px, py, pz, 0.0f);
  sorted[2*slot+1] = make_float4(nrm[3*i+0], nrm[3*i+1], nrm[3*i+2], 0.0f);
}

__global__ __launch_bounds__(128) void raster_cols(const float4* __restrict__ sorted,
                                                   const int* __restrict__ off,
                                                   float* __restrict__ vr) {
  int col = blockIdx.x;            // x*128 + y
  int x = col >> 7, y = col & 127;
  __shared__ float acc[3][128];
  for (int t = threadIdx.x; t < 384; t += 128) ((float*)acc)[t] = 0.0f;
  __syncthreads();
  #pragma unroll
  for (int q = 0; q < 4; q++) {
    int bx = (q & 2) ? x : (x + 127) & 127;
    int by = (q & 1) ? y : (y + 127) & 127;
    int b = (bx << 7) + by;
    int s = off[b], e = off[b + 1];
    for (int p = s + threadIdx.x; p < e; p += 128) {
      float4 P  = sorted[2*p];
      float4 Nm = sorted[2*p+1];
      float tx = P.x * 128.0f, ty = P.y * 128.0f, tz = P.z * 128.0f;
      float fx = tx - floorf(tx), fy = ty - floorf(ty), fz = tz - floorf(tz);
      int lz = ((int)floorf(tz)) & 127;
      int z1 = (lz + 1) & 127;
      float wx = (q & 2) ? (1.0f - fx) : fx;
      float wy = (q & 1) ? (1.0f - fy) : fy;
      float w0 = wx * wy * (1.0f - fz), w1 = wx * wy * fz;
      atomicAdd(&acc[0][lz], w0 * Nm.x); atomicAdd(&acc[0][z1], w1 * Nm.x);
      atomicAdd(&acc[1][lz], w0 * Nm.y); atomicAdd(&acc[1][z1], w1 * Nm.y);
      atomicAdd(&acc[2][lz], w0 * Nm.z); atomicAdd(&acc[2][z1], w1 * Nm.z);
    }
  }
  __syncthreads();
  int base = col << 7;
  for (int t = threadIdx.x; t < 384; t += 128) {
    int c = t >> 7, z = t & 127;
    vr[c * NCELLS + base + z] = acc[c][z];
  }
}

// ================= pass ZY: forward 2D (z,y) FFT per (x, grid) =================
// g=0: pack v0 + i*v1 ; g=1: v2. Output [w][x][ky].
__global__ __launch_bounds__(512) void pass_zy(const float* __restrict__ vr,
                                               float2* __restrict__ Zp,
                                               float2* __restrict__ Z2) {
  __shared__ float2 M[128][129];
  __shared__ float2 S[16][128];
  __shared__ float2 tw[128];
  int tid = threadIdx.x;
  init_tw(tw, tid);
  int x = blockIdx.x, g = blockIdx.y;
  const float* s0 = vr + (g ? 2 * NCELLS : 0);
  const float* s1 = vr + NCELLS;
  for (int e = tid; e < 16384; e += 512) {
    int y = e >> 7, z = e & 127;
    int gi = (x * 128 + y) * 128 + z;
    M[y][z] = g ? make_float2(s0[gi], 0.0f) : make_float2(s0[gi], s1[gi]);
  }
  __syncthreads();
  for (int gr = 0; gr < 8; gr++) fft16<-1>(&M[gr*16][0], 129, 1, S, tw, tid);  // z (rows)
  for (int gr = 0; gr < 8; gr++) fft16<-1>(&M[0][gr*16], 1, 129, S, tw, tid);  // y (cols)
  float2* D = g ? Z2 : Zp;
  for (int e = tid; e < 16384; e += 512) {
    int w = e >> 7, ky = e & 127;
    D[(w * 128 + x) * 128 + ky] = M[ky][w];
  }
}

// ================= pass XSPEC: fwd x-FFT + spectral/unpack + inv x-FFT =================
// Block (w, T): 16 ky-lines starting at 16T. Reads Zp primary + mirror tiles and Z2
// primary tile; writes chi (inv-x'd) in-place into Z2's primary tile.
__global__ __launch_bounds__(512) void pass_xspec(const float2* __restrict__ Zp,
                                                  float2* __restrict__ Z2) {
  __shared__ float2 Tp[16][129], Tm[16][129], T2[16][129];
  __shared__ float2 S[16][128];
  __shared__ float2 tw[128];
  int tid = threadIdx.x;
  init_tw(tw, tid);
  int w = blockIdx.x, T = blockIdx.y;
  int wm = (128 - w) & 127;
  int ky0 = T << 4;
  for (int e = tid; e < 2048; e += 512) {
    int xx = e >> 4, i = e & 15;
    int ky = ky0 + i;
    int kym = (128 - ky) & 127;
    Tp[i][xx] = Zp[(w  * 128 + xx) * 128 + ky];
    Tm[i][xx] = Zp[(wm * 128 + xx) * 128 + kym];
    T2[i][xx] = Z2[(w  * 128 + xx) * 128 + ky];
  }
  __syncthreads();
  fft16<-1>(&Tp[0][0], 129, 1, S, tw, tid);
  fft16<-1>(&Tm[0][0], 129, 1, S, tw, tid);
  fft16<-1>(&T2[0][0], 129, 1, S, tw, tid);
  float fz = (float)(w < 64 ? w : w - 128);
  for (int e = tid; e < 2048; e += 512) {
    int i = e >> 7, kx = e & 127;
    int ky = ky0 + i;
    int kxm = (128 - kx) & 127;
    float2 A  = Tp[i][kx];
    float2 Bm = Tm[i][kxm];          // Zp-hat at (-kx,-ky,-w)
    float2 v2 = T2[i][kx];
    float2 v0 = make_float2(0.5f * (A.x + Bm.x), 0.5f * (A.y - Bm.y));
    float2 v1 = make_float2(0.5f * (A.y + Bm.y), 0.5f * (Bm.x - A.x));
    float fx = (float)(kx < 64 ? kx : kx - 128);
    float fy = (float)(ky < 64 ? ky : ky - 128);
    float u2 = fx * fx + fy * fy + fz * fz;
    float gg = __expf(-0.0030517578125f * u2);   // -2*(5/128)^2*u2
    float coef = gg / (6.28318530717958648f * (u2 + 1e-6f)) * (1.0f / 2097152.0f);
    float dre = fx * v0.x + fy * v1.x + fz * v2.x;
    float dim = fx * v0.y + fy * v1.y + fz * v2.y;
    T2[i][kx] = make_float2(coef * dim, -coef * dre);  // (-i)*(a+bi) = (b,-a)
  }
  __syncthreads();
  fft16<1>(&T2[0][0], 129, 1, S, tw, tid);
  for (int e = tid; e < 2048; e += 512) {
    int xx = e >> 4, i = e & 15;
    Z2[(w * 128 + xx) * 128 + ky0 + i] = T2[i][xx];
  }
}

// ================= pass YZ_INV: inverse 2D (y,z) FFT per x, write real chi =================
__global__ __launch_bounds__(512) void pass_yz_inv(const float2* __restrict__ Zc,
                                                   float* __restrict__ chi) {
  __shared__ float2 M[128][129];
  __shared__ float2 S[16][128];
  __shared__ float2 tw[128];
  int tid = threadIdx.x;
  init_tw(tw, tid);
  int x = blockIdx.x;
  for (int e = tid; e < 16384; e += 512) {
    int w = e >> 7, ky = e & 127;
    M[w][ky] = Zc[(w * 128 + x) * 128 + ky];
  }
  __syncthreads();
  for (int gr = 0; gr < 8; gr++) fft16<1>(&M[gr*16][0], 129, 1, S, tw, tid);  // inv-y rows
  for (int gr = 0; gr < 8; gr++) fft16<1>(&M[0][gr*16], 1, 129, S, tw, tid);  // inv-z cols
  for (int e = tid; e < 16384; e += 512) {
    int y = e >> 7, z = e & 127;
    chi[(x * 128 + y) * 128 + z] = M[z][y].x;
  }
}

// ================= interpolation + mean, finalize =================
__global__ __launch_bounds__(256) void interp_mean(const float* __restrict__ pts,
                                                   const float* __restrict__ chi,
                                                   float* __restrict__ sum, int npts) {
  int i = blockIdx.x * 256 + threadIdx.x;
  float v = 0.0f;
  if (i < npts) {
    float tx = pts[3*i+0] * 128.0f, ty = pts[3*i+1] * 128.0f, tz = pts[3*i+2] * 128.0f;
    int lx = (int)floorf(tx), ly = (int)floorf(ty), lz = (int)floorf(tz);
    float fx = tx - (float)lx, fy = ty - (float)ly, fz = tz - (float)lz;
    lx &= 127; ly &= 127; lz &= 127;
    int hx = (lx + 1) & 127, hy = (ly + 1) & 127, hz = (lz + 1) & 127;
    #pragma unroll
    for (int c = 0; c < 8; c++) {
      int ix = (c & 4) ? hx : lx; float wx = (c & 4) ? fx : 1.0f - fx;
      int iy = (c & 2) ? hy : ly; float wy = (c & 2) ? fy : 1.0f - fy;
      int iz = (c & 1) ? hz : lz; float wz = (c & 1) ? fz : 1.0f - fz;
      v += wx * wy * wz * chi[(ix << 14) + (iy << 7) + iz];
    }
  }
  #pragma unroll
  for (int off = 32; off > 0; off >>= 1) v += __shfl_down(v, off, 64);
  if ((threadIdx.x & 63) == 0) atomicAdd(sum, v);
}

__global__ __launch_bounds__(256) void finalize(const float* __restrict__ chi,
                                                const float* __restrict__ sum,
                                                float* __restrict__ out, int npts) {
  int i = blockIdx.x * 256 + threadIdx.x;
  float mean = sum[0] / (float)npts;
  float chi0 = chi[0] - mean;
  float scale = 0.5f / fabsf(chi0);
  out[i] = scale * (chi[i] - mean);
}

// ================= launch =================
extern "C" void kernel_launch(void* const* d_in, const int* in_sizes, int n_in,
                              void* d_out, int out_size, void* d_ws, size_t ws_size,
                              hipStream_t stream) {
  const float* pts = (const float*)d_in[0];
  const float* nrm = (const float*)d_in[1];
  float* out = (float*)d_out;
  int npts = in_sizes[0] / 3;  // 131072

  char* p = (char*)d_ws;
  float2* Zp     = (float2*)p;  p += (size_t)NCELLS * sizeof(float2);     // 16.8 MB
  float2* Z2     = (float2*)p;  p += (size_t)NCELLS * sizeof(float2);     // 16.8 MB
  float*  vr     = (float*)p;   p += 3ull * NCELLS * sizeof(float);       // 25.2 MB
  float4* sorted = (float4*)p;  p += 2ull * 131072 * sizeof(float4);      // 4.2 MB
  float*  chi    = (float*)p;   p += (size_t)NCELLS * sizeof(float);      // 8.4 MB
  int*    counts = (int*)p;     p += 16384 * sizeof(int);
  float*  sum    = (float*)p;   p += sizeof(float);
  int*    off    = (int*)p;     p += 16385 * sizeof(int);
  int*    cur    = (int*)p;

  hipMemsetAsync(counts, 0, 16384 * sizeof(int) + sizeof(float), stream);  // counts + sum

  hist_kernel<<<(npts + 255) / 256, 256, 0, stream>>>(pts, counts, npts);
  scan16k<<<1, 1024, 0, stream>>>(counts, off, cur);
  scatter_kernel<<<(npts + 255) / 256, 256, 0, stream>>>(pts, nrm, cur, sorted, npts);
  raster_cols<<<16384, 128, 0, stream>>>(sorted, off, vr);

  pass_zy<<<dim3(128, 2), 512, 0, stream>>>(vr, Zp, Z2);
  pass_xspec<<<dim3(128, 8), 512, 0, stream>>>(Zp, Z2);
  pass_yz_inv<<<128, 512, 0, stream>>>(Z2, chi);

  interp_mean<<<(npts + 255) / 256, 256, 0, stream>>>(pts, chi, sum, npts);
  finalize<<<NCELLS / 256, 256, 0, stream>>>(chi, sum, out, npts);
}

// Round 5
// 223.329 us; speedup vs baseline: 1.2498x; 1.0345x over previous
//
#include <hip/hip_runtime.h>
#include <math.h>

#define NCELLS 2097152  // 128^3

// ================= complex helpers =================
__device__ __forceinline__ float2 cadd(float2 a, float2 b){ return make_float2(a.x+b.x, a.y+b.y); }
__device__ __forceinline__ float2 csub(float2 a, float2 b){ return make_float2(a.x-b.x, a.y-b.y); }
// multiply by w (DIR<0, forward) or conj(w) (DIR>0, inverse); table stores exp(-i theta)
template<int DIR>
__device__ __forceinline__ float2 ctw(float2 b, float2 w) {
  if (DIR < 0) return make_float2(b.x*w.x - b.y*w.y, b.x*w.y + b.y*w.x);
  else         return make_float2(b.x*w.x + b.y*w.y, b.y*w.x - b.x*w.y);
}

// tw[Ns+k] = exp(-i*pi*k/Ns), indices 1..127
__device__ __forceinline__ void init_tw(float2* tw, int tid) {
  if (tid >= 1 && tid < 128) {
    int Ns = 1 << (31 - __clz(tid));
    int k = tid - Ns;
    float ang = -3.14159265358979323846f * (float)k / (float)Ns;
    float s, c;
    sincosf(ang, &s, &c);
    tw[tid] = make_float2(c, s);
  }
}

// ===== mixed-radix Stockham FFT of 16 lines of 128, in-place at (base, line-stride ls,
// elem-stride es), scratch S[16][128], 512 threads, radix 4/4/4/2, natural->natural order.
template<int DIR>
__device__ __forceinline__ void fft16(float2* __restrict__ base, int ls, int es,
                                      float2 (*__restrict__ S)[128],
                                      const float2* __restrict__ tw, int tid) {
  int l = tid >> 5, j = tid & 31;
  float2* B = base + l * ls;
  { // stage 0: radix-4, Ns=1, B -> S (twiddles = 1)
    float2 a = B[j*es], b = B[(j+32)*es], c = B[(j+64)*es], d = B[(j+96)*es];
    float2 t0 = cadd(a,c), t1 = csub(a,c), t2 = cadd(b,d), t3s = csub(b,d);
    float2 t3 = (DIR<0) ? make_float2(t3s.y,-t3s.x) : make_float2(-t3s.y,t3s.x);
    int o = j << 2;
    S[l][o] = cadd(t0,t2); S[l][o+1] = cadd(t1,t3);
    S[l][o+2] = csub(t0,t2); S[l][o+3] = csub(t1,t3);
  }
  __syncthreads();
  { // stage 1: radix-4, Ns=4, S -> B
    int k = j & 3;
    float2 a = S[l][j], b = S[l][j+32], c = S[l][j+64], d = S[l][j+96];
    float2 w1 = tw[8+k], w2 = tw[4+k];
    float2 w3 = make_float2(w1.x*w2.x - w1.y*w2.y, w1.x*w2.y + w1.y*w2.x);
    b = ctw<DIR>(b,w1); c = ctw<DIR>(c,w2); d = ctw<DIR>(d,w3);
    float2 t0 = cadd(a,c), t1 = csub(a,c), t2 = cadd(b,d), t3s = csub(b,d);
    float2 t3 = (DIR<0) ? make_float2(t3s.y,-t3s.x) : make_float2(-t3s.y,t3s.x);
    int o = ((j>>2)<<4) + k;
    B[o*es] = cadd(t0,t2); B[(o+4)*es] = cadd(t1,t3);
    B[(o+8)*es] = csub(t0,t2); B[(o+12)*es] = csub(t1,t3);
  }
  __syncthreads();
  { // stage 2: radix-4, Ns=16, B -> S
    int k = j & 15;
    float2 a = B[j*es], b = B[(j+32)*es], c = B[(j+64)*es], d = B[(j+96)*es];
    float2 w1 = tw[32+k], w2 = tw[16+k];
    float2 w3 = make_float2(w1.x*w2.x - w1.y*w2.y, w1.x*w2.y + w1.y*w2.x);
    b = ctw<DIR>(b,w1); c = ctw<DIR>(c,w2); d = ctw<DIR>(d,w3);
    float2 t0 = cadd(a,c), t1 = csub(a,c), t2 = cadd(b,d), t3s = csub(b,d);
    float2 t3 = (DIR<0) ? make_float2(t3s.y,-t3s.x) : make_float2(-t3s.y,t3s.x);
    int o = ((j>>4)<<6) + k;
    S[l][o] = cadd(t0,t2); S[l][o+16] = cadd(t1,t3);
    S[l][o+32] = csub(t0,t2); S[l][o+48] = csub(t1,t3);
  }
  __syncthreads();
  // stage 3: radix-2, Ns=64, S -> B (1024 tasks, 2 per thread)
  #pragma unroll
  for (int q = 0; q < 2; q++) {
    int t = tid + q*512;
    int l2 = t >> 6, j2 = t & 63;
    float2 a = S[l2][j2], b = S[l2][j2+64];
    b = ctw<DIR>(b, tw[64+j2]);
    float2* D = base + l2*ls;
    D[j2*es] = cadd(a,b); D[(j2+64)*es] = csub(a,b);
  }
  __syncthreads();
}

// ================= binning: (x,y) bucket histogram / scan / scatter =================
__global__ __launch_bounds__(256) void hist_kernel(const float* __restrict__ pts,
                                                   int* __restrict__ counts, int npts) {
  int i = blockIdx.x * 256 + threadIdx.x;
  if (i >= npts) return;
  int lx = ((int)floorf(pts[3*i+0] * 128.0f)) & 127;
  int ly = ((int)floorf(pts[3*i+1] * 128.0f)) & 127;
  atomicAdd(counts + ((lx << 7) + ly), 1);
}

__global__ __launch_bounds__(1024) void scan16k(const int* __restrict__ counts,
                                                int* __restrict__ off,
                                                int* __restrict__ cur) {
  __shared__ int part[1024];
  int t = threadIdx.x;
  int local[16]; int s = 0;
  #pragma unroll
  for (int k = 0; k < 16; k++) { local[k] = s; s += counts[t * 16 + k]; }
  part[t] = s;
  __syncthreads();
  for (int d = 1; d < 1024; d <<= 1) {
    int v = (t >= d) ? part[t - d] : 0;
    __syncthreads();
    part[t] += v;
    __syncthreads();
  }
  int base = (t == 0) ? 0 : part[t - 1];
  #pragma unroll
  for (int k = 0; k < 16; k++) {
    int o = base + local[k];
    off[t * 16 + k] = o;
    cur[t * 16 + k] = o;
  }
  if (t == 1023) off[16384] = part[1023];
}

__global__ __launch_bounds__(256) void scatter_kernel(const float* __restrict__ pts,
                                                      const float* __restrict__ nrm,
                                                      int* __restrict__ cur,
                                                      float4* __restrict__ sorted, int npts) {
  int i = blockIdx.x * 256 + threadIdx.x;
  if (i >= npts) return;
  float px = pts[3*i+0], py = pts[3*i+1], pz = pts[3*i+2];
  int lx = ((int)floorf(px * 128.0f)) & 127;
  int ly = ((int)floorf(py * 128.0f)) & 127;
  int slot = atomicAdd(cur + ((lx << 7) + ly), 1);
  sorted[2*slot]   = make_float4(px, py, pz, 0.0f);
  sorted[2*slot+1] = make_float4(nrm[3*i+0], nrm[3*i+1], nrm[3*i+2], 0.0f);
}

// ================= pass ZY: fused raster + forward 2D (z,y) FFT per (x, grid) =============
// Points touching plane x are two contiguous sorted ranges: bucket rows bx=x (weight 1-fx)
// and bx=x-1 (weight fx). g=0: v0 + i*v1 ; g=1: v2. Output [w][x][ky].
__global__ __launch_bounds__(512) void pass_zy(const float4* __restrict__ sorted,
                                               const int* __restrict__ off,
                                               float2* __restrict__ Zp,
                                               float2* __restrict__ Z2) {
  __shared__ float2 M[128][129];
  __shared__ float2 S[16][128];
  __shared__ float2 tw[128];
  int tid = threadIdx.x;
  init_tw(tw, tid);
  int x = blockIdx.x, g = blockIdx.y;
  for (int e = tid; e < 16384; e += 512) M[e >> 7][e & 127] = make_float2(0.0f, 0.0f);
  __syncthreads();
  #pragma unroll
  for (int side = 0; side < 2; side++) {
    int bx = side ? ((x + 127) & 127) : x;
    int s = off[bx << 7], e0 = off[(bx << 7) + 128];
    for (int p = s + tid; p < e0; p += 512) {
      float4 P  = sorted[2*p];
      float4 Nm = sorted[2*p+1];
      float tx = P.x*128.0f, ty = P.y*128.0f, tz = P.z*128.0f;
      float fx = tx - floorf(tx), fy = ty - floorf(ty), fz = tz - floorf(tz);
      int ly = ((int)floorf(ty)) & 127, lz = ((int)floorf(tz)) & 127;
      int y1 = (ly + 1) & 127, z1 = (lz + 1) & 127;
      float wx = side ? fx : (1.0f - fx);
      float w00 = wx*(1.0f-fy)*(1.0f-fz), w01 = wx*(1.0f-fy)*fz;
      float w10 = wx*fy*(1.0f-fz),        w11 = wx*fy*fz;
      if (g == 0) {
        atomicAdd(&M[ly][lz].x, w00*Nm.x); atomicAdd(&M[ly][lz].y, w00*Nm.y);
        atomicAdd(&M[ly][z1].x, w01*Nm.x); atomicAdd(&M[ly][z1].y, w01*Nm.y);
        atomicAdd(&M[y1][lz].x, w10*Nm.x); atomicAdd(&M[y1][lz].y, w10*Nm.y);
        atomicAdd(&M[y1][z1].x, w11*Nm.x); atomicAdd(&M[y1][z1].y, w11*Nm.y);
      } else {
        atomicAdd(&M[ly][lz].x, w00*Nm.z);
        atomicAdd(&M[ly][z1].x, w01*Nm.z);
        atomicAdd(&M[y1][lz].x, w10*Nm.z);
        atomicAdd(&M[y1][z1].x, w11*Nm.z);
      }
    }
  }
  __syncthreads();
  for (int gr = 0; gr < 8; gr++) fft16<-1>(&M[gr*16][0], 129, 1, S, tw, tid);  // z (rows)
  for (int gr = 0; gr < 8; gr++) fft16<-1>(&M[0][gr*16], 1, 129, S, tw, tid);  // y (cols)
  float2* D = g ? Z2 : Zp;
  for (int e = tid; e < 16384; e += 512) {
    int w = e >> 7, ky = e & 127;
    D[(w * 128 + x) * 128 + ky] = M[ky][w];
  }
}

// ================= pass XSPEC: fwd x-FFT + spectral/unpack + inv x-FFT =================
__global__ __launch_bounds__(512) void pass_xspec(const float2* __restrict__ Zp,
                                                  float2* __restrict__ Z2) {
  __shared__ float2 Tp[16][129], Tm[16][129], T2[16][129];
  __shared__ float2 S[16][128];
  __shared__ float2 tw[128];
  int tid = threadIdx.x;
  init_tw(tw, tid);
  int w = blockIdx.x, T = blockIdx.y;
  int wm = (128 - w) & 127;
  int ky0 = T << 4;
  for (int e = tid; e < 2048; e += 512) {
    int xx = e >> 4, i = e & 15;
    int ky = ky0 + i;
    int kym = (128 - ky) & 127;
    Tp[i][xx] = Zp[(w  * 128 + xx) * 128 + ky];
    Tm[i][xx] = Zp[(wm * 128 + xx) * 128 + kym];
    T2[i][xx] = Z2[(w  * 128 + xx) * 128 + ky];
  }
  __syncthreads();
  fft16<-1>(&Tp[0][0], 129, 1, S, tw, tid);
  fft16<-1>(&Tm[0][0], 129, 1, S, tw, tid);
  fft16<-1>(&T2[0][0], 129, 1, S, tw, tid);
  float fz = (float)(w < 64 ? w : w - 128);
  for (int e = tid; e < 2048; e += 512) {
    int i = e >> 7, kx = e & 127;
    int ky = ky0 + i;
    int kxm = (128 - kx) & 127;
    float2 A  = Tp[i][kx];
    float2 Bm = Tm[i][kxm];          // Zp-hat at (-kx,-ky,-w)
    float2 v2 = T2[i][kx];
    float2 v0 = make_float2(0.5f * (A.x + Bm.x), 0.5f * (A.y - Bm.y));
    float2 v1 = make_float2(0.5f * (A.y + Bm.y), 0.5f * (Bm.x - A.x));
    float fx = (float)(kx < 64 ? kx : kx - 128);
    float fy = (float)(ky < 64 ? ky : ky - 128);
    float u2 = fx * fx + fy * fy + fz * fz;
    float gg = __expf(-0.0030517578125f * u2);   // -2*(5/128)^2*u2
    float coef = gg / (6.28318530717958648f * (u2 + 1e-6f)) * (1.0f / 2097152.0f);
    float dre = fx * v0.x + fy * v1.x + fz * v2.x;
    float dim = fx * v0.y + fy * v1.y + fz * v2.y;
    T2[i][kx] = make_float2(coef * dim, -coef * dre);  // (-i)*(a+bi) = (b,-a)
  }
  __syncthreads();
  fft16<1>(&T2[0][0], 129, 1, S, tw, tid);
  for (int e = tid; e < 2048; e += 512) {
    int xx = e >> 4, i = e & 15;
    Z2[(w * 128 + xx) * 128 + ky0 + i] = T2[i][xx];
  }
}

// ================= pass YZ_INV: inverse 2D (y,z) FFT per x, write real chi =================
__global__ __launch_bounds__(512) void pass_yz_inv(const float2* __restrict__ Zc,
                                                   float* __restrict__ chi) {
  __shared__ float2 M[128][129];
  __shared__ float2 S[16][128];
  __shared__ float2 tw[128];
  int tid = threadIdx.x;
  init_tw(tw, tid);
  int x = blockIdx.x;
  for (int e = tid; e < 16384; e += 512) {
    int w = e >> 7, ky = e & 127;
    M[w][ky] = Zc[(w * 128 + x) * 128 + ky];
  }
  __syncthreads();
  for (int gr = 0; gr < 8; gr++) fft16<1>(&M[gr*16][0], 129, 1, S, tw, tid);  // inv-y rows
  for (int gr = 0; gr < 8; gr++) fft16<1>(&M[0][gr*16], 1, 129, S, tw, tid);  // inv-z cols
  for (int e = tid; e < 16384; e += 512) {
    int y = e >> 7, z = e & 127;
    chi[(x * 128 + y) * 128 + z] = M[z][y].x;
  }
}

// ================= interpolation + mean, finalize =================
__global__ __launch_bounds__(256) void interp_mean(const float* __restrict__ pts,
                                                   const float* __restrict__ chi,
                                                   float* __restrict__ sum, int npts) {
  int i = blockIdx.x * 256 + threadIdx.x;
  float v = 0.0f;
  if (i < npts) {
    float tx = pts[3*i+0] * 128.0f, ty = pts[3*i+1] * 128.0f, tz = pts[3*i+2] * 128.0f;
    int lx = (int)floorf(tx), ly = (int)floorf(ty), lz = (int)floorf(tz);
    float fx = tx - (float)lx, fy = ty - (float)ly, fz = tz - (float)lz;
    lx &= 127; ly &= 127; lz &= 127;
    int hx = (lx + 1) & 127, hy = (ly + 1) & 127, hz = (lz + 1) & 127;
    #pragma unroll
    for (int c = 0; c < 8; c++) {
      int ix = (c & 4) ? hx : lx; float wx = (c & 4) ? fx : 1.0f - fx;
      int iy = (c & 2) ? hy : ly; float wy = (c & 2) ? fy : 1.0f - fy;
      int iz = (c & 1) ? hz : lz; float wz = (c & 1) ? fz : 1.0f - fz;
      v += wx * wy * wz * chi[(ix << 14) + (iy << 7) + iz];
    }
  }
  #pragma unroll
  for (int off = 32; off > 0; off >>= 1) v += __shfl_down(v, off, 64);
  if ((threadIdx.x & 63) == 0) atomicAdd(sum, v);
}

__global__ __launch_bounds__(256) void finalize(const float* __restrict__ chi,
                                                const float* __restrict__ sum,
                                                float* __restrict__ out, int npts) {
  int i = blockIdx.x * 256 + threadIdx.x;
  float mean = sum[0] / (float)npts;
  float chi0 = chi[0] - mean;
  float scale = 0.5f / fabsf(chi0);
  out[i] = scale * (chi[i] - mean);
}

// ================= launch =================
extern "C" void kernel_launch(void* const* d_in, const int* in_sizes, int n_in,
                              void* d_out, int out_size, void* d_ws, size_t ws_size,
                              hipStream_t stream) {
  const float* pts = (const float*)d_in[0];
  const float* nrm = (const float*)d_in[1];
  float* out = (float*)d_out;
  int npts = in_sizes[0] / 3;  // 131072

  char* p = (char*)d_ws;
  float2* Zp     = (float2*)p;  p += (size_t)NCELLS * sizeof(float2);     // 16.8 MB
  float2* Z2     = (float2*)p;  p += (size_t)NCELLS * sizeof(float2);     // 16.8 MB
  float4* sorted = (float4*)p;  p += 2ull * 131072 * sizeof(float4);      // 4.2 MB
  float*  chi    = (float*)p;   p += (size_t)NCELLS * sizeof(float);      // 8.4 MB
  int*    counts = (int*)p;     p += 16384 * sizeof(int);
  float*  sum    = (float*)p;   p += sizeof(float);
  int*    off    = (int*)p;     p += 16385 * sizeof(int);
  int*    cur    = (int*)p;

  hipMemsetAsync(counts, 0, 16384 * sizeof(int) + sizeof(float), stream);  // counts + sum

  hist_kernel<<<(npts + 255) / 256, 256, 0, stream>>>(pts, counts, npts);
  scan16k<<<1, 1024, 0, stream>>>(counts, off, cur);
  scatter_kernel<<<(npts + 255) / 256, 256, 0, stream>>>(pts, nrm, cur, sorted, npts);

  pass_zy<<<dim3(128, 2), 512, 0, stream>>>(sorted, off, Zp, Z2);
  pass_xspec<<<dim3(128, 8), 512, 0, stream>>>(Zp, Z2);
  pass_yz_inv<<<128, 512, 0, stream>>>(Z2, chi);

  interp_mean<<<(npts + 255) / 256, 256, 0, stream>>>(pts, chi, sum, npts);
  finalize<<<NCELLS / 256, 256, 0, stream>>>(chi, sum, out, npts);
}

// Round 6
// 218.911 us; speedup vs baseline: 1.2750x; 1.0202x over previous
//
#include <hip/hip_runtime.h>
#include <math.h>

#define NCELLS 2097152  // 128^3

// ================= complex helpers =================
__device__ __forceinline__ float2 cadd(float2 a, float2 b){ return make_float2(a.x+b.x, a.y+b.y); }
__device__ __forceinline__ float2 csub(float2 a, float2 b){ return make_float2(a.x-b.x, a.y-b.y); }
template<int DIR>
__device__ __forceinline__ float2 ctw(float2 b, float2 w) {
  if (DIR < 0) return make_float2(b.x*w.x - b.y*w.y, b.x*w.y + b.y*w.x);
  else         return make_float2(b.x*w.x + b.y*w.y, b.y*w.x - b.x*w.y);
}

// tw[Ns+k] = exp(-i*pi*k/Ns), indices 1..127
__device__ __forceinline__ void init_tw(float2* tw, int tid) {
  if (tid >= 1 && tid < 128) {
    int Ns = 1 << (31 - __clz(tid));
    int k = tid - Ns;
    float ang = -3.14159265358979323846f * (float)k / (float)Ns;
    float s, c;
    sincosf(ang, &s, &c);
    tw[tid] = make_float2(c, s);
  }
}

// ===== mixed-radix Stockham FFT of 16 lines of 128, in-place at (base, line-stride ls,
// elem-stride es), scratch S[16][128], 512 threads, radix 4/4/4/2, natural->natural order.
template<int DIR>
__device__ __forceinline__ void fft16(float2* __restrict__ base, int ls, int es,
                                      float2 (*__restrict__ S)[128],
                                      const float2* __restrict__ tw, int tid) {
  int l = tid >> 5, j = tid & 31;
  float2* B = base + l * ls;
  { // stage 0: radix-4, Ns=1, B -> S
    float2 a = B[j*es], b = B[(j+32)*es], c = B[(j+64)*es], d = B[(j+96)*es];
    float2 t0 = cadd(a,c), t1 = csub(a,c), t2 = cadd(b,d), t3s = csub(b,d);
    float2 t3 = (DIR<0) ? make_float2(t3s.y,-t3s.x) : make_float2(-t3s.y,t3s.x);
    int o = j << 2;
    S[l][o] = cadd(t0,t2); S[l][o+1] = cadd(t1,t3);
    S[l][o+2] = csub(t0,t2); S[l][o+3] = csub(t1,t3);
  }
  __syncthreads();
  { // stage 1: radix-4, Ns=4, S -> B
    int k = j & 3;
    float2 a = S[l][j], b = S[l][j+32], c = S[l][j+64], d = S[l][j+96];
    float2 w1 = tw[8+k], w2 = tw[4+k];
    float2 w3 = make_float2(w1.x*w2.x - w1.y*w2.y, w1.x*w2.y + w1.y*w2.x);
    b = ctw<DIR>(b,w1); c = ctw<DIR>(c,w2); d = ctw<DIR>(d,w3);
    float2 t0 = cadd(a,c), t1 = csub(a,c), t2 = cadd(b,d), t3s = csub(b,d);
    float2 t3 = (DIR<0) ? make_float2(t3s.y,-t3s.x) : make_float2(-t3s.y,t3s.x);
    int o = ((j>>2)<<4) + k;
    B[o*es] = cadd(t0,t2); B[(o+4)*es] = cadd(t1,t3);
    B[(o+8)*es] = csub(t0,t2); B[(o+12)*es] = csub(t1,t3);
  }
  __syncthreads();
  { // stage 2: radix-4, Ns=16, B -> S
    int k = j & 15;
    float2 a = B[j*es], b = B[(j+32)*es], c = B[(j+64)*es], d = B[(j+96)*es];
    float2 w1 = tw[32+k], w2 = tw[16+k];
    float2 w3 = make_float2(w1.x*w2.x - w1.y*w2.y, w1.x*w2.y + w1.y*w2.x);
    b = ctw<DIR>(b,w1); c = ctw<DIR>(c,w2); d = ctw<DIR>(d,w3);
    float2 t0 = cadd(a,c), t1 = csub(a,c), t2 = cadd(b,d), t3s = csub(b,d);
    float2 t3 = (DIR<0) ? make_float2(t3s.y,-t3s.x) : make_float2(-t3s.y,t3s.x);
    int o = ((j>>4)<<6) + k;
    S[l][o] = cadd(t0,t2); S[l][o+16] = cadd(t1,t3);
    S[l][o+32] = csub(t0,t2); S[l][o+48] = csub(t1,t3);
  }
  __syncthreads();
  // stage 3: radix-2, Ns=64, S -> B
  #pragma unroll
  for (int q = 0; q < 2; q++) {
    int t = tid + q*512;
    int l2 = t >> 6, j2 = t & 63;
    float2 a = S[l2][j2], b = S[l2][j2+64];
    b = ctw<DIR>(b, tw[64+j2]);
    float2* D = base + l2*ls;
    D[j2*es] = cadd(a,b); D[(j2+64)*es] = csub(a,b);
  }
  __syncthreads();
}

// ================= binning =================
__global__ __launch_bounds__(256) void hist_kernel(const float* __restrict__ pts,
                                                   int* __restrict__ counts, int npts) {
  int i = blockIdx.x * 256 + threadIdx.x;
  if (i >= npts) return;
  int lx = ((int)floorf(pts[3*i+0] * 128.0f)) & 127;
  int ly = ((int)floorf(pts[3*i+1] * 128.0f)) & 127;
  atomicAdd(counts + ((lx << 7) + ly), 1);
}

__global__ __launch_bounds__(1024) void scan16k(const int* __restrict__ counts,
                                                int* __restrict__ off,
                                                int* __restrict__ cur) {
  __shared__ int part[1024];
  int t = threadIdx.x;
  int local[16]; int s = 0;
  #pragma unroll
  for (int k = 0; k < 16; k++) { local[k] = s; s += counts[t * 16 + k]; }
  part[t] = s;
  __syncthreads();
  for (int d = 1; d < 1024; d <<= 1) {
    int v = (t >= d) ? part[t - d] : 0;
    __syncthreads();
    part[t] += v;
    __syncthreads();
  }
  int base = (t == 0) ? 0 : part[t - 1];
  #pragma unroll
  for (int k = 0; k < 16; k++) {
    int o = base + local[k];
    off[t * 16 + k] = o;
    cur[t * 16 + k] = o;
  }
  if (t == 1023) off[16384] = part[1023];
}

__global__ __launch_bounds__(256) void scatter_kernel(const float* __restrict__ pts,
                                                      const float* __restrict__ nrm,
                                                      int* __restrict__ cur,
                                                      float4* __restrict__ sorted, int npts) {
  int i = blockIdx.x * 256 + threadIdx.x;
  if (i >= npts) return;
  float px = pts[3*i+0], py = pts[3*i+1], pz = pts[3*i+2];
  int lx = ((int)floorf(px * 128.0f)) & 127;
  int ly = ((int)floorf(py * 128.0f)) & 127;
  int slot = atomicAdd(cur + ((lx << 7) + ly), 1);
  sorted[2*slot]   = make_float4(px, py, pz, 0.0f);
  sorted[2*slot+1] = make_float4(nrm[3*i+0], nrm[3*i+1], nrm[3*i+2], 0.0f);
}

// one block per (x,y) column: gather 4 neighbor buckets, accumulate z-column in LDS.
__global__ __launch_bounds__(128) void raster_cols(const float4* __restrict__ sorted,
                                                   const int* __restrict__ off,
                                                   float* __restrict__ vr) {
  int col = blockIdx.x;            // x*128 + y
  int x = col >> 7, y = col & 127;
  __shared__ float acc[3][128];
  for (int t = threadIdx.x; t < 384; t += 128) ((float*)acc)[t] = 0.0f;
  __syncthreads();
  #pragma unroll
  for (int q = 0; q < 4; q++) {
    int bx = (q & 2) ? x : (x + 127) & 127;
    int by = (q & 1) ? y : (y + 127) & 127;
    int b = (bx << 7) + by;
    int s = off[b], e = off[b + 1];
    for (int p = s + threadIdx.x; p < e; p += 128) {
      float4 P  = sorted[2*p];
      float4 Nm = sorted[2*p+1];
      float tx = P.x * 128.0f, ty = P.y * 128.0f, tz = P.z * 128.0f;
      float fx = tx - floorf(tx), fy = ty - floorf(ty), fz = tz - floorf(tz);
      int lz = ((int)floorf(tz)) & 127;
      int z1 = (lz + 1) & 127;
      float wx = (q & 2) ? (1.0f - fx) : fx;
      float wy = (q & 1) ? (1.0f - fy) : fy;
      float w0 = wx * wy * (1.0f - fz), w1 = wx * wy * fz;
      atomicAdd(&acc[0][lz], w0 * Nm.x); atomicAdd(&acc[0][z1], w1 * Nm.x);
      atomicAdd(&acc[1][lz], w0 * Nm.y); atomicAdd(&acc[1][z1], w1 * Nm.y);
      atomicAdd(&acc[2][lz], w0 * Nm.z); atomicAdd(&acc[2][z1], w1 * Nm.z);
    }
  }
  __syncthreads();
  int base = col << 7;
  for (int t = threadIdx.x; t < 384; t += 128) {
    int c = t >> 7, z = t & 127;
    vr[c * NCELLS + base + z] = acc[c][z];
  }
}

// ================= fwd_z: z-FFT of 16 columns, store transposed [x][w][y] ============
// g=0: Zp = FFTz(v0 + i v1); g=1: Z2 = FFTz(v2).
__global__ __launch_bounds__(512, 6) void fwd_z(const float* __restrict__ vr,
                                                float2* __restrict__ Zp,
                                                float2* __restrict__ Z2) {
  __shared__ float2 sc[16][129];
  __shared__ float2 S[16][128];
  __shared__ float2 tw[128];
  int tid = threadIdx.x;
  init_tw(tw, tid);
  int x = blockIdx.x >> 3, y0 = (blockIdx.x & 7) << 4;
  int g = blockIdx.y;
  int colbase = (x << 7) + y0;     // 16 consecutive (x,y) columns
  const float* s0 = vr + (g ? 2 * NCELLS : 0);
  const float* s1 = vr + NCELLS;
  for (int e = tid; e < 2048; e += 512) {
    int l = e >> 7, z = e & 127;
    int gi = (colbase + l) * 128 + z;
    sc[l][z] = g ? make_float2(s0[gi], 0.0f) : make_float2(s0[gi], s1[gi]);
  }
  __syncthreads();
  fft16<-1>(&sc[0][0], 129, 1, S, tw, tid);
  float2* D = g ? Z2 : Zp;
  for (int e = tid; e < 2048; e += 512) {
    int w = e >> 4, l = e & 15;
    D[x * 16384 + w * 128 + y0 + l] = sc[l][w];
  }
}

// ================= fwd_y: y-FFT on contiguous lines, in place =================
// layout [x][w][y]; block = (x, 16 consecutive w), g selects Zp/Z2.
__global__ __launch_bounds__(512, 6) void fwd_y(float2* __restrict__ Zp,
                                                float2* __restrict__ Z2) {
  __shared__ float2 sc[16][129];
  __shared__ float2 S[16][128];
  __shared__ float2 tw[128];
  int tid = threadIdx.x;
  init_tw(tw, tid);
  float2* D = (blockIdx.y ? Z2 : Zp) + blockIdx.x * 2048;  // 16 lines of 128
  for (int e = tid; e < 2048; e += 512) sc[e >> 7][e & 127] = D[e];
  __syncthreads();
  fft16<-1>(&sc[0][0], 129, 1, S, tw, tid);
  for (int e = tid; e < 2048; e += 512) D[e] = sc[e >> 7][e & 127];
}

// ================= xspec: fwd x-FFT + spectral/unpack + inv x-FFT =================
// layout [x][w][ky]; block (w, ky-tile T). Writes chi-spectrum (inv-x'd) into Z2.
__global__ __launch_bounds__(512, 4) void pass_xspec(const float2* __restrict__ Zp,
                                                     float2* __restrict__ Z2) {
  __shared__ float2 Tp[16][129], Tm[16][129], T2[16][129];
  __shared__ float2 S[16][128];
  __shared__ float2 tw[128];
  int tid = threadIdx.x;
  init_tw(tw, tid);
  int w = blockIdx.x, T = blockIdx.y;
  int wm = (128 - w) & 127;
  int ky0 = T << 4;
  for (int e = tid; e < 2048; e += 512) {
    int xx = e >> 4, i = e & 15;
    int ky = ky0 + i;
    int kym = (128 - ky) & 127;
    Tp[i][xx] = Zp[xx * 16384 + w  * 128 + ky];
    Tm[i][xx] = Zp[xx * 16384 + wm * 128 + kym];
    T2[i][xx] = Z2[xx * 16384 + w  * 128 + ky];
  }
  __syncthreads();
  fft16<-1>(&Tp[0][0], 129, 1, S, tw, tid);
  fft16<-1>(&Tm[0][0], 129, 1, S, tw, tid);
  fft16<-1>(&T2[0][0], 129, 1, S, tw, tid);
  float fz = (float)(w < 64 ? w : w - 128);
  for (int e = tid; e < 2048; e += 512) {
    int i = e >> 7, kx = e & 127;
    int ky = ky0 + i;
    int kxm = (128 - kx) & 127;
    float2 A  = Tp[i][kx];
    float2 Bm = Tm[i][kxm];          // Zp-hat at (-kx,-ky,-w)
    float2 v2 = T2[i][kx];
    float2 v0 = make_float2(0.5f * (A.x + Bm.x), 0.5f * (A.y - Bm.y));
    float2 v1 = make_float2(0.5f * (A.y + Bm.y), 0.5f * (Bm.x - A.x));
    float fx = (float)(kx < 64 ? kx : kx - 128);
    float fy = (float)(ky < 64 ? ky : ky - 128);
    float u2 = fx * fx + fy * fy + fz * fz;
    float gg = __expf(-0.0030517578125f * u2);   // -2*(5/128)^2*u2
    float coef = gg / (6.28318530717958648f * (u2 + 1e-6f)) * (1.0f / 2097152.0f);
    float dre = fx * v0.x + fy * v1.x + fz * v2.x;
    float dim = fx * v0.y + fy * v1.y + fz * v2.y;
    T2[i][kx] = make_float2(coef * dim, -coef * dre);  // (-i)*(a+bi) = (b,-a)
  }
  __syncthreads();
  fft16<1>(&T2[0][0], 129, 1, S, tw, tid);
  for (int e = tid; e < 2048; e += 512) {
    int xx = e >> 4, i = e & 15;
    Z2[xx * 16384 + w * 128 + ky0 + i] = T2[i][xx];
  }
}

// ================= inv_y: inverse y-FFT on contiguous lines, in place =================
__global__ __launch_bounds__(512, 6) void inv_y(float2* __restrict__ Z2) {
  __shared__ float2 sc[16][129];
  __shared__ float2 S[16][128];
  __shared__ float2 tw[128];
  int tid = threadIdx.x;
  init_tw(tw, tid);
  float2* D = Z2 + blockIdx.x * 2048;
  for (int e = tid; e < 2048; e += 512) sc[e >> 7][e & 127] = D[e];
  __syncthreads();
  fft16<1>(&sc[0][0], 129, 1, S, tw, tid);
  for (int e = tid; e < 2048; e += 512) D[e] = sc[e >> 7][e & 127];
}

// ================= inv_z: inverse w-FFT (tile 16y x 128w), write real chi [x][y][z] =====
__global__ __launch_bounds__(512, 6) void inv_z(const float2* __restrict__ Z2,
                                                float* __restrict__ chi) {
  __shared__ float2 sc[16][129];
  __shared__ float2 S[16][128];
  __shared__ float2 tw[128];
  int tid = threadIdx.x;
  init_tw(tw, tid);
  int x = blockIdx.x >> 3, y0 = (blockIdx.x & 7) << 4;
  for (int e = tid; e < 2048; e += 512) {
    int w = e >> 4, i = e & 15;
    sc[i][w] = Z2[x * 16384 + w * 128 + y0 + i];
  }
  __syncthreads();
  fft16<1>(&sc[0][0], 129, 1, S, tw, tid);
  for (int e = tid; e < 2048; e += 512) {
    int i = e >> 7, z = e & 127;
    chi[(x * 128 + y0 + i) * 128 + z] = sc[i][z].x;
  }
}

// ================= interpolation + mean, finalize =================
__global__ __launch_bounds__(256) void interp_mean(const float* __restrict__ pts,
                                                   const float* __restrict__ chi,
                                                   float* __restrict__ sum, int npts) {
  int i = blockIdx.x * 256 + threadIdx.x;
  float v = 0.0f;
  if (i < npts) {
    float tx = pts[3*i+0] * 128.0f, ty = pts[3*i+1] * 128.0f, tz = pts[3*i+2] * 128.0f;
    int lx = (int)floorf(tx), ly = (int)floorf(ty), lz = (int)floorf(tz);
    float fx = tx - (float)lx, fy = ty - (float)ly, fz = tz - (float)lz;
    lx &= 127; ly &= 127; lz &= 127;
    int hx = (lx + 1) & 127, hy = (ly + 1) & 127, hz = (lz + 1) & 127;
    #pragma unroll
    for (int c = 0; c < 8; c++) {
      int ix = (c & 4) ? hx : lx; float wx = (c & 4) ? fx : 1.0f - fx;
      int iy = (c & 2) ? hy : ly; float wy = (c & 2) ? fy : 1.0f - fy;
      int iz = (c & 1) ? hz : lz; float wz = (c & 1) ? fz : 1.0f - fz;
      v += wx * wy * wz * chi[(ix << 14) + (iy << 7) + iz];
    }
  }
  #pragma unroll
  for (int off = 32; off > 0; off >>= 1) v += __shfl_down(v, off, 64);
  if ((threadIdx.x & 63) == 0) atomicAdd(sum, v);
}

__global__ __launch_bounds__(256) void finalize(const float* __restrict__ chi,
                                                const float* __restrict__ sum,
                                                float* __restrict__ out, int npts) {
  int i = blockIdx.x * 256 + threadIdx.x;
  float mean = sum[0] / (float)npts;
  float chi0 = chi[0] - mean;
  float scale = 0.5f / fabsf(chi0);
  out[i] = scale * (chi[i] - mean);
}

// ================= launch =================
extern "C" void kernel_launch(void* const* d_in, const int* in_sizes, int n_in,
                              void* d_out, int out_size, void* d_ws, size_t ws_size,
                              hipStream_t stream) {
  const float* pts = (const float*)d_in[0];
  const float* nrm = (const float*)d_in[1];
  float* out = (float*)d_out;
  int npts = in_sizes[0] / 3;  // 131072

  char* p = (char*)d_ws;
  float2* Zp     = (float2*)p;  p += (size_t)NCELLS * sizeof(float2);     // 16.8 MB
  float2* Z2     = (float2*)p;  p += (size_t)NCELLS * sizeof(float2);     // 16.8 MB
  float*  vr     = (float*)p;   p += 3ull * NCELLS * sizeof(float);       // 25.2 MB
  float4* sorted = (float4*)p;  p += 2ull * 131072 * sizeof(float4);      // 4.2 MB
  float*  chi    = (float*)p;   p += (size_t)NCELLS * sizeof(float);      // 8.4 MB
  int*    counts = (int*)p;     p += 16384 * sizeof(int);
  float*  sum    = (float*)p;   p += sizeof(float);
  int*    off    = (int*)p;     p += 16385 * sizeof(int);
  int*    cur    = (int*)p;

  hipMemsetAsync(counts, 0, 16384 * sizeof(int) + sizeof(float), stream);  // counts + sum

  hist_kernel<<<(npts + 255) / 256, 256, 0, stream>>>(pts, counts, npts);
  scan16k<<<1, 1024, 0, stream>>>(counts, off, cur);
  scatter_kernel<<<(npts + 255) / 256, 256, 0, stream>>>(pts, nrm, cur, sorted, npts);
  raster_cols<<<16384, 128, 0, stream>>>(sorted, off, vr);

  fwd_z<<<dim3(1024, 2), 512, 0, stream>>>(vr, Zp, Z2);
  fwd_y<<<dim3(1024, 2), 512, 0, stream>>>(Zp, Z2);
  pass_xspec<<<dim3(128, 8), 512, 0, stream>>>(Zp, Z2);
  inv_y<<<1024, 512, 0, stream>>>(Z2);
  inv_z<<<1024, 512, 0, stream>>>(Z2, chi);

  interp_mean<<<(npts + 255) / 256, 256, 0, stream>>>(pts, chi, sum, npts);
  finalize<<<NCELLS / 256, 256, 0, stream>>>(chi, sum, out, npts);
}

// Round 7
// 196.254 us; speedup vs baseline: 1.4222x; 1.1154x over previous
//
#include <hip/hip_runtime.h>
#include <math.h>

#define NCELLS 2097152  // 128^3
#define CAP 32          // bucket capacity (mean occupancy 8; P(>32) ~ 1e-10)

// ================= complex helpers =================
__device__ __forceinline__ float2 cadd(float2 a, float2 b){ return make_float2(a.x+b.x, a.y+b.y); }
__device__ __forceinline__ float2 csub(float2 a, float2 b){ return make_float2(a.x-b.x, a.y-b.y); }
template<int DIR>
__device__ __forceinline__ float2 ctw(float2 b, float2 w) {
  if (DIR < 0) return make_float2(b.x*w.x - b.y*w.y, b.x*w.y + b.y*w.x);
  else         return make_float2(b.x*w.x + b.y*w.y, b.y*w.x - b.x*w.y);
}

// tw[Ns+k] = exp(-i*pi*k/Ns), indices 1..127
__device__ __forceinline__ void init_tw(float2* tw, int tid) {
  if (tid >= 1 && tid < 128) {
    int Ns = 1 << (31 - __clz(tid));
    int k = tid - Ns;
    float ang = -3.14159265358979323846f * (float)k / (float)Ns;
    float s, c;
    sincosf(ang, &s, &c);
    tw[tid] = make_float2(c, s);
  }
}

// ===== mixed-radix Stockham FFT of 16 lines of 128, in-place at (base, line-stride ls,
// elem-stride es), scratch S[16][128], 512 threads, radix 4/4/4/2, natural->natural order.
template<int DIR>
__device__ __forceinline__ void fft16(float2* __restrict__ base, int ls, int es,
                                      float2 (*__restrict__ S)[128],
                                      const float2* __restrict__ tw, int tid) {
  int l = tid >> 5, j = tid & 31;
  float2* B = base + l * ls;
  { // stage 0: radix-4, Ns=1, B -> S
    float2 a = B[j*es], b = B[(j+32)*es], c = B[(j+64)*es], d = B[(j+96)*es];
    float2 t0 = cadd(a,c), t1 = csub(a,c), t2 = cadd(b,d), t3s = csub(b,d);
    float2 t3 = (DIR<0) ? make_float2(t3s.y,-t3s.x) : make_float2(-t3s.y,t3s.x);
    int o = j << 2;
    S[l][o] = cadd(t0,t2); S[l][o+1] = cadd(t1,t3);
    S[l][o+2] = csub(t0,t2); S[l][o+3] = csub(t1,t3);
  }
  __syncthreads();
  { // stage 1: radix-4, Ns=4, S -> B
    int k = j & 3;
    float2 a = S[l][j], b = S[l][j+32], c = S[l][j+64], d = S[l][j+96];
    float2 w1 = tw[8+k], w2 = tw[4+k];
    float2 w3 = make_float2(w1.x*w2.x - w1.y*w2.y, w1.x*w2.y + w1.y*w2.x);
    b = ctw<DIR>(b,w1); c = ctw<DIR>(c,w2); d = ctw<DIR>(d,w3);
    float2 t0 = cadd(a,c), t1 = csub(a,c), t2 = cadd(b,d), t3s = csub(b,d);
    float2 t3 = (DIR<0) ? make_float2(t3s.y,-t3s.x) : make_float2(-t3s.y,t3s.x);
    int o = ((j>>2)<<4) + k;
    B[o*es] = cadd(t0,t2); B[(o+4)*es] = cadd(t1,t3);
    B[(o+8)*es] = csub(t0,t2); B[(o+12)*es] = csub(t1,t3);
  }
  __syncthreads();
  { // stage 2: radix-4, Ns=16, B -> S
    int k = j & 15;
    float2 a = B[j*es], b = B[(j+32)*es], c = B[(j+64)*es], d = B[(j+96)*es];
    float2 w1 = tw[32+k], w2 = tw[16+k];
    float2 w3 = make_float2(w1.x*w2.x - w1.y*w2.y, w1.x*w2.y + w1.y*w2.x);
    b = ctw<DIR>(b,w1); c = ctw<DIR>(c,w2); d = ctw<DIR>(d,w3);
    float2 t0 = cadd(a,c), t1 = csub(a,c), t2 = cadd(b,d), t3s = csub(b,d);
    float2 t3 = (DIR<0) ? make_float2(t3s.y,-t3s.x) : make_float2(-t3s.y,t3s.x);
    int o = ((j>>4)<<6) + k;
    S[l][o] = cadd(t0,t2); S[l][o+16] = cadd(t1,t3);
    S[l][o+32] = csub(t0,t2); S[l][o+48] = csub(t1,t3);
  }
  __syncthreads();
  // stage 3: radix-2, Ns=64, S -> B
  #pragma unroll
  for (int q = 0; q < 2; q++) {
    int t = tid + q*512;
    int l2 = t >> 6, j2 = t & 63;
    float2 a = S[l2][j2], b = S[l2][j2+64];
    b = ctw<DIR>(b, tw[64+j2]);
    float2* D = base + l2*ls;
    D[j2*es] = cadd(a,b); D[(j2+64)*es] = csub(a,b);
  }
  __syncthreads();
}

// ================= direct bucket scatter (fixed capacity, no scan) =================
__global__ __launch_bounds__(256) void scatter_direct(const float* __restrict__ pts,
                                                      const float* __restrict__ nrm,
                                                      int* __restrict__ counts,
                                                      float4* __restrict__ bkt, int npts) {
  int i = blockIdx.x * 256 + threadIdx.x;
  if (i >= npts) return;
  float px = pts[3*i+0], py = pts[3*i+1], pz = pts[3*i+2];
  int lx = ((int)floorf(px * 128.0f)) & 127;
  int ly = ((int)floorf(py * 128.0f)) & 127;
  int b = (lx << 7) + ly;
  int slot = atomicAdd(counts + b, 1);
  if (slot < CAP) {
    bkt[(size_t)(b * CAP + slot) * 2]     = make_float4(px, py, pz, 0.0f);
    bkt[(size_t)(b * CAP + slot) * 2 + 1] = make_float4(nrm[3*i+0], nrm[3*i+1], nrm[3*i+2], 0.0f);
  }
}

// ================= fwd_zr: fused raster + z-FFT (both grids), store [x][w][y] =========
// Block: (x, y0..y0+15, all z). Points: buckets bx in {x-1,x}, by in [y0-1, y0+15].
__global__ __launch_bounds__(512, 6) void fwd_zr(const float4* __restrict__ bkt,
                                                 const int* __restrict__ counts,
                                                 float2* __restrict__ Zp,
                                                 float2* __restrict__ Z2) {
  __shared__ float2 sp[16][129];   // v0 + i*v1
  __shared__ float2 s2[16][129];   // v2
  __shared__ float2 S[16][128];
  __shared__ float2 tw[128];
  int tid = threadIdx.x;
  init_tw(tw, tid);
  int x = blockIdx.x >> 3, y0 = (blockIdx.x & 7) << 4;
  for (int e = tid; e < 16 * 129; e += 512) {
    (&sp[0][0])[e] = make_float2(0.0f, 0.0f);
    (&s2[0][0])[e] = make_float2(0.0f, 0.0f);
  }
  __syncthreads();
  // scatter: 2 sides x 17 buckets x CAP slots
  for (int t = tid; t < 2 * 17 * CAP; t += 512) {
    int side = t / (17 * CAP);
    int jj = t - side * (17 * CAP);
    int j = jj >> 5, slot = jj & 31;          // CAP == 32
    int by = (y0 - 1 + j) & 127;
    int bx = side ? ((x + 127) & 127) : x;
    int b = (bx << 7) + by;
    int cnt = counts[b]; if (cnt > CAP) cnt = CAP;
    if (slot < cnt) {
      float4 P  = bkt[(size_t)(b * CAP + slot) * 2];
      float4 Nm = bkt[(size_t)(b * CAP + slot) * 2 + 1];
      float tx = P.x*128.0f, ty = P.y*128.0f, tz = P.z*128.0f;
      float fx = tx - floorf(tx), fy = ty - floorf(ty), fz = tz - floorf(tz);
      int ly = ((int)floorf(ty)) & 127, lz = ((int)floorf(tz)) & 127;
      int z1 = (lz + 1) & 127;
      float wx = side ? fx : (1.0f - fx);
      #pragma unroll
      for (int yc = 0; yc < 2; yc++) {
        int yy = yc ? ((ly + 1) & 127) : ly;
        float wy = yc ? fy : (1.0f - fy);
        int l = (yy - y0) & 127;
        if (l < 16) {
          float w0 = wx*wy*(1.0f - fz), w1 = wx*wy*fz;
          atomicAdd(&sp[l][lz].x, w0*Nm.x); atomicAdd(&sp[l][lz].y, w0*Nm.y);
          atomicAdd(&sp[l][z1].x, w1*Nm.x); atomicAdd(&sp[l][z1].y, w1*Nm.y);
          atomicAdd(&s2[l][lz].x, w0*Nm.z);
          atomicAdd(&s2[l][z1].x, w1*Nm.z);
        }
      }
    }
  }
  __syncthreads();
  fft16<-1>(&sp[0][0], 129, 1, S, tw, tid);
  for (int e = tid; e < 2048; e += 512) {
    int w = e >> 4, l = e & 15;
    Zp[x * 16384 + w * 128 + y0 + l] = sp[l][w];
  }
  fft16<-1>(&s2[0][0], 129, 1, S, tw, tid);
  for (int e = tid; e < 2048; e += 512) {
    int w = e >> 4, l = e & 15;
    Z2[x * 16384 + w * 128 + y0 + l] = s2[l][w];
  }
}

// ================= fwd_y: y-FFT on contiguous lines, in place =================
__global__ __launch_bounds__(512, 6) void fwd_y(float2* __restrict__ Zp,
                                                float2* __restrict__ Z2) {
  __shared__ float2 sc[16][129];
  __shared__ float2 S[16][128];
  __shared__ float2 tw[128];
  int tid = threadIdx.x;
  init_tw(tw, tid);
  float2* D = (blockIdx.y ? Z2 : Zp) + blockIdx.x * 2048;  // 16 lines of 128
  for (int e = tid; e < 2048; e += 512) sc[e >> 7][e & 127] = D[e];
  __syncthreads();
  fft16<-1>(&sc[0][0], 129, 1, S, tw, tid);
  for (int e = tid; e < 2048; e += 512) D[e] = sc[e >> 7][e & 127];
}

// ================= xspec: fwd x-FFT + spectral/unpack + inv x-FFT =================
// layout [x][w][ky]; block (w, ky-tile T). Writes chi-spectrum (inv-x'd) into Z2.
__global__ __launch_bounds__(512, 4) void pass_xspec(const float2* __restrict__ Zp,
                                                     float2* __restrict__ Z2) {
  __shared__ float2 Tp[16][129], Tm[16][129], T2[16][129];
  __shared__ float2 S[16][128];
  __shared__ float2 tw[128];
  int tid = threadIdx.x;
  init_tw(tw, tid);
  int w = blockIdx.x, T = blockIdx.y;
  int wm = (128 - w) & 127;
  int ky0 = T << 4;
  for (int e = tid; e < 2048; e += 512) {
    int xx = e >> 4, i = e & 15;
    int ky = ky0 + i;
    int kym = (128 - ky) & 127;
    Tp[i][xx] = Zp[xx * 16384 + w  * 128 + ky];
    Tm[i][xx] = Zp[xx * 16384 + wm * 128 + kym];
    T2[i][xx] = Z2[xx * 16384 + w  * 128 + ky];
  }
  __syncthreads();
  fft16<-1>(&Tp[0][0], 129, 1, S, tw, tid);
  fft16<-1>(&Tm[0][0], 129, 1, S, tw, tid);
  fft16<-1>(&T2[0][0], 129, 1, S, tw, tid);
  float fz = (float)(w < 64 ? w : w - 128);
  for (int e = tid; e < 2048; e += 512) {
    int i = e >> 7, kx = e & 127;
    int ky = ky0 + i;
    int kxm = (128 - kx) & 127;
    float2 A  = Tp[i][kx];
    float2 Bm = Tm[i][kxm];          // Zp-hat at (-kx,-ky,-w)
    float2 v2 = T2[i][kx];
    float2 v0 = make_float2(0.5f * (A.x + Bm.x), 0.5f * (A.y - Bm.y));
    float2 v1 = make_float2(0.5f * (A.y + Bm.y), 0.5f * (Bm.x - A.x));
    float fx = (float)(kx < 64 ? kx : kx - 128);
    float fy = (float)(ky < 64 ? ky : ky - 128);
    float u2 = fx * fx + fy * fy + fz * fz;
    float gg = __expf(-0.0030517578125f * u2);   // -2*(5/128)^2*u2
    float coef = gg / (6.28318530717958648f * (u2 + 1e-6f)) * (1.0f / 2097152.0f);
    float dre = fx * v0.x + fy * v1.x + fz * v2.x;
    float dim = fx * v0.y + fy * v1.y + fz * v2.y;
    T2[i][kx] = make_float2(coef * dim, -coef * dre);  // (-i)*(a+bi) = (b,-a)
  }
  __syncthreads();
  fft16<1>(&T2[0][0], 129, 1, S, tw, tid);
  for (int e = tid; e < 2048; e += 512) {
    int xx = e >> 4, i = e & 15;
    Z2[xx * 16384 + w * 128 + ky0 + i] = T2[i][xx];
  }
}

// ================= inv_y: inverse y-FFT on contiguous lines, in place =================
__global__ __launch_bounds__(512, 6) void inv_y(float2* __restrict__ Z2) {
  __shared__ float2 sc[16][129];
  __shared__ float2 S[16][128];
  __shared__ float2 tw[128];
  int tid = threadIdx.x;
  init_tw(tw, tid);
  float2* D = Z2 + blockIdx.x * 2048;
  for (int e = tid; e < 2048; e += 512) sc[e >> 7][e & 127] = D[e];
  __syncthreads();
  fft16<1>(&sc[0][0], 129, 1, S, tw, tid);
  for (int e = tid; e < 2048; e += 512) D[e] = sc[e >> 7][e & 127];
}

// ================= inv_z: inverse w-FFT (tile 16y x 128w), write real chi [x][y][z] =====
__global__ __launch_bounds__(512, 6) void inv_z(const float2* __restrict__ Z2,
                                                float* __restrict__ chi) {
  __shared__ float2 sc[16][129];
  __shared__ float2 S[16][128];
  __shared__ float2 tw[128];
  int tid = threadIdx.x;
  init_tw(tw, tid);
  int x = blockIdx.x >> 3, y0 = (blockIdx.x & 7) << 4;
  for (int e = tid; e < 2048; e += 512) {
    int w = e >> 4, i = e & 15;
    sc[i][w] = Z2[x * 16384 + w * 128 + y0 + i];
  }
  __syncthreads();
  fft16<1>(&sc[0][0], 129, 1, S, tw, tid);
  for (int e = tid; e < 2048; e += 512) {
    int i = e >> 7, z = e & 127;
    chi[(x * 128 + y0 + i) * 128 + z] = sc[i][z].x;
  }
}

// ================= interpolation + mean, finalize =================
__global__ __launch_bounds__(256) void interp_mean(const float* __restrict__ pts,
                                                   const float* __restrict__ chi,
                                                   float* __restrict__ sum, int npts) {
  int i = blockIdx.x * 256 + threadIdx.x;
  float v = 0.0f;
  if (i < npts) {
    float tx = pts[3*i+0] * 128.0f, ty = pts[3*i+1] * 128.0f, tz = pts[3*i+2] * 128.0f;
    int lx = (int)floorf(tx), ly = (int)floorf(ty), lz = (int)floorf(tz);
    float fx = tx - (float)lx, fy = ty - (float)ly, fz = tz - (float)lz;
    lx &= 127; ly &= 127; lz &= 127;
    int hx = (lx + 1) & 127, hy = (ly + 1) & 127, hz = (lz + 1) & 127;
    #pragma unroll
    for (int c = 0; c < 8; c++) {
      int ix = (c & 4) ? hx : lx; float wx = (c & 4) ? fx : 1.0f - fx;
      int iy = (c & 2) ? hy : ly; float wy = (c & 2) ? fy : 1.0f - fy;
      int iz = (c & 1) ? hz : lz; float wz = (c & 1) ? fz : 1.0f - fz;
      v += wx * wy * wz * chi[(ix << 14) + (iy << 7) + iz];
    }
  }
  #pragma unroll
  for (int off = 32; off > 0; off >>= 1) v += __shfl_down(v, off, 64);
  if ((threadIdx.x & 63) == 0) atomicAdd(sum, v);
}

__global__ __launch_bounds__(256) void finalize(const float* __restrict__ chi,
                                                const float* __restrict__ sum,
                                                float* __restrict__ out, int npts) {
  int i = blockIdx.x * 256 + threadIdx.x;
  float mean = sum[0] / (float)npts;
  float chi0 = chi[0] - mean;
  float scale = 0.5f / fabsf(chi0);
  out[i] = scale * (chi[i] - mean);
}

// ================= launch =================
extern "C" void kernel_launch(void* const* d_in, const int* in_sizes, int n_in,
                              void* d_out, int out_size, void* d_ws, size_t ws_size,
                              hipStream_t stream) {
  const float* pts = (const float*)d_in[0];
  const float* nrm = (const float*)d_in[1];
  float* out = (float*)d_out;
  int npts = in_sizes[0] / 3;  // 131072

  char* p = (char*)d_ws;
  float2* Zp     = (float2*)p;  p += (size_t)NCELLS * sizeof(float2);       // 16.8 MB
  float2* Z2     = (float2*)p;  p += (size_t)NCELLS * sizeof(float2);       // 16.8 MB
  float4* bkt    = (float4*)p;  p += (size_t)16384 * CAP * 2 * sizeof(float4); // 16.8 MB
  float*  chi    = (float*)p;   p += (size_t)NCELLS * sizeof(float);        // 8.4 MB
  int*    counts = (int*)p;     p += 16384 * sizeof(int);
  float*  sum    = (float*)p;

  hipMemsetAsync(counts, 0, 16384 * sizeof(int) + sizeof(float), stream);  // counts + sum

  scatter_direct<<<(npts + 255) / 256, 256, 0, stream>>>(pts, nrm, counts, bkt, npts);
  fwd_zr<<<1024, 512, 0, stream>>>(bkt, counts, Zp, Z2);
  fwd_y<<<dim3(1024, 2), 512, 0, stream>>>(Zp, Z2);
  pass_xspec<<<dim3(128, 8), 512, 0, stream>>>(Zp, Z2);
  inv_y<<<1024, 512, 0, stream>>>(Z2);
  inv_z<<<1024, 512, 0, stream>>>(Z2, chi);

  interp_mean<<<(npts + 255) / 256, 256, 0, stream>>>(pts, chi, sum, npts);
  finalize<<<NCELLS / 256, 256, 0, stream>>>(chi, sum, out, npts);
}

// Round 8
// 186.428 us; speedup vs baseline: 1.4972x; 1.0527x over previous
//
#include <hip/hip_runtime.h>
#include <math.h>

#define NCELLS 2097152  // 128^3
#define CAP 32          // bucket capacity (mean occupancy 8; P(>32) ~ 1e-10)

// ================= complex helpers =================
__device__ __forceinline__ float2 cadd(float2 a, float2 b){ return make_float2(a.x+b.x, a.y+b.y); }
__device__ __forceinline__ float2 csub(float2 a, float2 b){ return make_float2(a.x-b.x, a.y-b.y); }
template<int DIR>
__device__ __forceinline__ float2 ctw(float2 b, float2 w) {
  if (DIR < 0) return make_float2(b.x*w.x - b.y*w.y, b.x*w.y + b.y*w.x);
  else         return make_float2(b.x*w.x + b.y*w.y, b.y*w.x - b.x*w.y);
}

// tw[Ns+k] = exp(-i*pi*k/Ns), indices 1..127
__device__ __forceinline__ void init_tw(float2* tw, int tid) {
  if (tid >= 1 && tid < 128) {
    int Ns = 1 << (31 - __clz(tid));
    int k = tid - Ns;
    float ang = -3.14159265358979323846f * (float)k / (float)Ns;
    float s, c;
    sincosf(ang, &s, &c);
    tw[tid] = make_float2(c, s);
  }
}

// ===== mixed-radix Stockham FFT of 16 lines of 128, in-place at (base, line-stride ls,
// elem-stride es), scratch S[16][128], 512 threads, radix 4/4/4/2, natural->natural order.
template<int DIR>
__device__ __forceinline__ void fft16(float2* __restrict__ base, int ls, int es,
                                      float2 (*__restrict__ S)[128],
                                      const float2* __restrict__ tw, int tid) {
  int l = tid >> 5, j = tid & 31;
  float2* B = base + l * ls;
  { // stage 0: radix-4, Ns=1, B -> S
    float2 a = B[j*es], b = B[(j+32)*es], c = B[(j+64)*es], d = B[(j+96)*es];
    float2 t0 = cadd(a,c), t1 = csub(a,c), t2 = cadd(b,d), t3s = csub(b,d);
    float2 t3 = (DIR<0) ? make_float2(t3s.y,-t3s.x) : make_float2(-t3s.y,t3s.x);
    int o = j << 2;
    S[l][o] = cadd(t0,t2); S[l][o+1] = cadd(t1,t3);
    S[l][o+2] = csub(t0,t2); S[l][o+3] = csub(t1,t3);
  }
  __syncthreads();
  { // stage 1: radix-4, Ns=4, S -> B
    int k = j & 3;
    float2 a = S[l][j], b = S[l][j+32], c = S[l][j+64], d = S[l][j+96];
    float2 w1 = tw[8+k], w2 = tw[4+k];
    float2 w3 = make_float2(w1.x*w2.x - w1.y*w2.y, w1.x*w2.y + w1.y*w2.x);
    b = ctw<DIR>(b,w1); c = ctw<DIR>(c,w2); d = ctw<DIR>(d,w3);
    float2 t0 = cadd(a,c), t1 = csub(a,c), t2 = cadd(b,d), t3s = csub(b,d);
    float2 t3 = (DIR<0) ? make_float2(t3s.y,-t3s.x) : make_float2(-t3s.y,t3s.x);
    int o = ((j>>2)<<4) + k;
    B[o*es] = cadd(t0,t2); B[(o+4)*es] = cadd(t1,t3);
    B[(o+8)*es] = csub(t0,t2); B[(o+12)*es] = csub(t1,t3);
  }
  __syncthreads();
  { // stage 2: radix-4, Ns=16, B -> S
    int k = j & 15;
    float2 a = B[j*es], b = B[(j+32)*es], c = B[(j+64)*es], d = B[(j+96)*es];
    float2 w1 = tw[32+k], w2 = tw[16+k];
    float2 w3 = make_float2(w1.x*w2.x - w1.y*w2.y, w1.x*w2.y + w1.y*w2.x);
    b = ctw<DIR>(b,w1); c = ctw<DIR>(c,w2); d = ctw<DIR>(d,w3);
    float2 t0 = cadd(a,c), t1 = csub(a,c), t2 = cadd(b,d), t3s = csub(b,d);
    float2 t3 = (DIR<0) ? make_float2(t3s.y,-t3s.x) : make_float2(-t3s.y,t3s.x);
    int o = ((j>>4)<<6) + k;
    S[l][o] = cadd(t0,t2); S[l][o+16] = cadd(t1,t3);
    S[l][o+32] = csub(t0,t2); S[l][o+48] = csub(t1,t3);
  }
  __syncthreads();
  // stage 3: radix-2, Ns=64, S -> B
  #pragma unroll
  for (int q = 0; q < 2; q++) {
    int t = tid + q*512;
    int l2 = t >> 6, j2 = t & 63;
    float2 a = S[l2][j2], b = S[l2][j2+64];
    b = ctw<DIR>(b, tw[64+j2]);
    float2* D = base + l2*ls;
    D[j2*es] = cadd(a,b); D[(j2+64)*es] = csub(a,b);
  }
  __syncthreads();
}

// ================= direct bucket scatter (fixed capacity, no scan) =================
__global__ __launch_bounds__(256) void scatter_direct(const float* __restrict__ pts,
                                                      const float* __restrict__ nrm,
                                                      int* __restrict__ counts,
                                                      float4* __restrict__ bkt, int npts) {
  int i = blockIdx.x * 256 + threadIdx.x;
  if (i >= npts) return;
  float px = pts[3*i+0], py = pts[3*i+1], pz = pts[3*i+2];
  int lx = ((int)floorf(px * 128.0f)) & 127;
  int ly = ((int)floorf(py * 128.0f)) & 127;
  int b = (lx << 7) + ly;
  int slot = atomicAdd(counts + b, 1);
  if (slot < CAP) {
    bkt[(size_t)(b * CAP + slot) * 2]     = make_float4(px, py, pz, 0.0f);
    bkt[(size_t)(b * CAP + slot) * 2 + 1] = make_float4(nrm[3*i+0], nrm[3*i+1], nrm[3*i+2], 0.0f);
  }
}

// ================= fwd_zr: fused raster + z-FFT + Hermitian z-unpack ===============
// Block: (x, y0..y0+15, all z). Outputs V0,V1,V2 = z-spectra of v0,v1,v2 for w in [0,64],
// layout [w][x][y] (slice stride 16384).
__global__ __launch_bounds__(512, 6) void fwd_zr(const float4* __restrict__ bkt,
                                                 const int* __restrict__ counts,
                                                 float2* __restrict__ V0,
                                                 float2* __restrict__ V1,
                                                 float2* __restrict__ V2) {
  __shared__ float2 sp[16][129];   // v0 + i*v1
  __shared__ float2 s2[16][129];   // v2
  __shared__ float2 S[16][128];
  __shared__ float2 tw[128];
  int tid = threadIdx.x;
  init_tw(tw, tid);
  int x = blockIdx.x >> 3, y0 = (blockIdx.x & 7) << 4;
  for (int e = tid; e < 16 * 129; e += 512) {
    (&sp[0][0])[e] = make_float2(0.0f, 0.0f);
    (&s2[0][0])[e] = make_float2(0.0f, 0.0f);
  }
  __syncthreads();
  // scatter: 2 sides x 17 buckets x CAP slots
  for (int t = tid; t < 2 * 17 * CAP; t += 512) {
    int side = t / (17 * CAP);
    int jj = t - side * (17 * CAP);
    int j = jj >> 5, slot = jj & 31;          // CAP == 32
    int by = (y0 - 1 + j) & 127;
    int bx = side ? ((x + 127) & 127) : x;
    int b = (bx << 7) + by;
    int cnt = counts[b]; if (cnt > CAP) cnt = CAP;
    if (slot < cnt) {
      float4 P  = bkt[(size_t)(b * CAP + slot) * 2];
      float4 Nm = bkt[(size_t)(b * CAP + slot) * 2 + 1];
      float tx = P.x*128.0f, ty = P.y*128.0f, tz = P.z*128.0f;
      float fx = tx - floorf(tx), fy = ty - floorf(ty), fz = tz - floorf(tz);
      int ly = ((int)floorf(ty)) & 127, lz = ((int)floorf(tz)) & 127;
      int z1 = (lz + 1) & 127;
      float wx = side ? fx : (1.0f - fx);
      #pragma unroll
      for (int yc = 0; yc < 2; yc++) {
        int yy = yc ? ((ly + 1) & 127) : ly;
        float wy = yc ? fy : (1.0f - fy);
        int l = (yy - y0) & 127;
        if (l < 16) {
          float w0 = wx*wy*(1.0f - fz), w1 = wx*wy*fz;
          atomicAdd(&sp[l][lz].x, w0*Nm.x); atomicAdd(&sp[l][lz].y, w0*Nm.y);
          atomicAdd(&sp[l][z1].x, w1*Nm.x); atomicAdd(&sp[l][z1].y, w1*Nm.y);
          atomicAdd(&s2[l][lz].x, w0*Nm.z);
          atomicAdd(&s2[l][z1].x, w1*Nm.z);
        }
      }
    }
  }
  __syncthreads();
  fft16<-1>(&sp[0][0], 129, 1, S, tw, tid);
  // Hermitian unpack along w (line-local): v0hat=(A+conj(B))/2, v1hat=(A-conj(B))/(2i)
  for (int e = tid; e < 65 * 16; e += 512) {
    int w = e >> 4, l = e & 15;
    float2 A = sp[l][w];
    float2 B = sp[l][(128 - w) & 127];
    size_t o = (size_t)w * 16384 + x * 128 + y0 + l;
    V0[o] = make_float2(0.5f * (A.x + B.x), 0.5f * (A.y - B.y));
    V1[o] = make_float2(0.5f * (A.y + B.y), 0.5f * (B.x - A.x));
  }
  fft16<-1>(&s2[0][0], 129, 1, S, tw, tid);
  for (int e = tid; e < 65 * 16; e += 512) {
    int w = e >> 4, l = e & 15;
    V2[(size_t)w * 16384 + x * 128 + y0 + l] = s2[l][w];
  }
}

// ================= fwd_y: y-FFT on contiguous lines, in place (3 channels) ============
__global__ __launch_bounds__(512, 6) void fwd_y(float2* __restrict__ V0,
                                                float2* __restrict__ V1,
                                                float2* __restrict__ V2) {
  __shared__ float2 sc[16][129];
  __shared__ float2 S[16][128];
  __shared__ float2 tw[128];
  int tid = threadIdx.x;
  init_tw(tw, tid);
  float2* D = (blockIdx.y == 0 ? V0 : blockIdx.y == 1 ? V1 : V2) + (size_t)blockIdx.x * 2048;
  for (int e = tid; e < 2048; e += 512) sc[e >> 7][e & 127] = D[e];
  __syncthreads();
  fft16<-1>(&sc[0][0], 129, 1, S, tw, tid);
  for (int e = tid; e < 2048; e += 512) D[e] = sc[e >> 7][e & 127];
}

// ================= xspec: fwd x-FFT (3ch) + spectral + inv x-FFT, in place into V0 =====
// Block (w in [0,64], ky-tile T). No mirrors needed: channels are true spectra.
__global__ __launch_bounds__(512, 4) void pass_xspec(float2* __restrict__ V0,
                                                     const float2* __restrict__ V1,
                                                     const float2* __restrict__ V2) {
  __shared__ float2 T0[16][129], T1[16][129], T2[16][129];
  __shared__ float2 S[16][128];
  __shared__ float2 tw[128];
  int tid = threadIdx.x;
  init_tw(tw, tid);
  int w = blockIdx.x, T = blockIdx.y;
  int ky0 = T << 4;
  for (int e = tid; e < 2048; e += 512) {
    int xx = e >> 4, i = e & 15;
    size_t o = (size_t)w * 16384 + xx * 128 + ky0 + i;
    T0[i][xx] = V0[o];
    T1[i][xx] = V1[o];
    T2[i][xx] = V2[o];
  }
  __syncthreads();
  fft16<-1>(&T0[0][0], 129, 1, S, tw, tid);
  fft16<-1>(&T1[0][0], 129, 1, S, tw, tid);
  fft16<-1>(&T2[0][0], 129, 1, S, tw, tid);
  float fz = (float)(w < 64 ? w : w - 128);
  for (int e = tid; e < 2048; e += 512) {
    int i = e >> 7, kx = e & 127;
    int ky = ky0 + i;
    float2 v0 = T0[i][kx], v1 = T1[i][kx], v2 = T2[i][kx];
    float fx = (float)(kx < 64 ? kx : kx - 128);
    float fy = (float)(ky < 64 ? ky : ky - 128);
    float u2 = fx * fx + fy * fy + fz * fz;
    float gg = __expf(-0.0030517578125f * u2);   // -2*(5/128)^2*u2
    float coef = gg / (6.28318530717958648f * (u2 + 1e-6f)) * (1.0f / 2097152.0f);
    float dre = fx * v0.x + fy * v1.x + fz * v2.x;
    float dim = fx * v0.y + fy * v1.y + fz * v2.y;
    T0[i][kx] = make_float2(coef * dim, -coef * dre);  // (-i)*(a+bi) = (b,-a)
  }
  __syncthreads();
  fft16<1>(&T0[0][0], 129, 1, S, tw, tid);
  for (int e = tid; e < 2048; e += 512) {
    int xx = e >> 4, i = e & 15;
    V0[(size_t)w * 16384 + xx * 128 + ky0 + i] = T0[i][xx];
  }
}

// ================= inv_y: inverse y-FFT on contiguous lines, in place (V0) =============
__global__ __launch_bounds__(512, 6) void inv_y(float2* __restrict__ V0) {
  __shared__ float2 sc[16][129];
  __shared__ float2 S[16][128];
  __shared__ float2 tw[128];
  int tid = threadIdx.x;
  init_tw(tw, tid);
  float2* D = V0 + (size_t)blockIdx.x * 2048;
  for (int e = tid; e < 2048; e += 512) sc[e >> 7][e & 127] = D[e];
  __syncthreads();
  fft16<1>(&sc[0][0], 129, 1, S, tw, tid);
  for (int e = tid; e < 2048; e += 512) D[e] = sc[e >> 7][e & 127];
}

// ================= inv_z: Hermitian c2r inverse w-FFT, write real chi [x][y][z] =========
// C(128-w,x,y) = conj(C(w,x,y)): load w in [0,64], mirror in LDS, inverse FFT, take .x.
__global__ __launch_bounds__(512, 6) void inv_z(const float2* __restrict__ V0,
                                                float* __restrict__ chi) {
  __shared__ float2 sc[16][129];
  __shared__ float2 S[16][128];
  __shared__ float2 tw[128];
  int tid = threadIdx.x;
  init_tw(tw, tid);
  int x = blockIdx.x >> 3, y0 = (blockIdx.x & 7) << 4;
  for (int e = tid; e < 65 * 16; e += 512) {
    int w = e >> 4, i = e & 15;
    sc[i][w] = V0[(size_t)w * 16384 + x * 128 + y0 + i];
  }
  __syncthreads();
  for (int e = tid; e < 63 * 16; e += 512) {
    int w = 65 + (e >> 4), i = e & 15;
    float2 c = sc[i][128 - w];
    sc[i][w] = make_float2(c.x, -c.y);
  }
  __syncthreads();
  fft16<1>(&sc[0][0], 129, 1, S, tw, tid);
  for (int e = tid; e < 2048; e += 512) {
    int i = e >> 7, z = e & 127;
    chi[(x * 128 + y0 + i) * 128 + z] = sc[i][z].x;
  }
}

// ================= interpolation + mean, finalize =================
__global__ __launch_bounds__(256) void interp_mean(const float* __restrict__ pts,
                                                   const float* __restrict__ chi,
                                                   float* __restrict__ sum, int npts) {
  int i = blockIdx.x * 256 + threadIdx.x;
  float v = 0.0f;
  if (i < npts) {
    float tx = pts[3*i+0] * 128.0f, ty = pts[3*i+1] * 128.0f, tz = pts[3*i+2] * 128.0f;
    int lx = (int)floorf(tx), ly = (int)floorf(ty), lz = (int)floorf(tz);
    float fx = tx - (float)lx, fy = ty - (float)ly, fz = tz - (float)lz;
    lx &= 127; ly &= 127; lz &= 127;
    int hx = (lx + 1) & 127, hy = (ly + 1) & 127, hz = (lz + 1) & 127;
    #pragma unroll
    for (int c = 0; c < 8; c++) {
      int ix = (c & 4) ? hx : lx; float wx = (c & 4) ? fx : 1.0f - fx;
      int iy = (c & 2) ? hy : ly; float wy = (c & 2) ? fy : 1.0f - fy;
      int iz = (c & 1) ? hz : lz; float wz = (c & 1) ? fz : 1.0f - fz;
      v += wx * wy * wz * chi[(ix << 14) + (iy << 7) + iz];
    }
  }
  #pragma unroll
  for (int off = 32; off > 0; off >>= 1) v += __shfl_down(v, off, 64);
  if ((threadIdx.x & 63) == 0) atomicAdd(sum, v);
}

__global__ __launch_bounds__(256) void finalize(const float* __restrict__ chi,
                                                const float* __restrict__ sum,
                                                float* __restrict__ out, int npts) {
  int i = blockIdx.x * 256 + threadIdx.x;
  float mean = sum[0] / (float)npts;
  float chi0 = chi[0] - mean;
  float scale = 0.5f / fabsf(chi0);
  out[i] = scale * (chi[i] - mean);
}

// ================= launch =================
extern "C" void kernel_launch(void* const* d_in, const int* in_sizes, int n_in,
                              void* d_out, int out_size, void* d_ws, size_t ws_size,
                              hipStream_t stream) {
  const float* pts = (const float*)d_in[0];
  const float* nrm = (const float*)d_in[1];
  float* out = (float*)d_out;
  int npts = in_sizes[0] / 3;  // 131072

  const size_t HSLICES = 65ull * 16384;  // half-spectrum elems per channel
  char* p = (char*)d_ws;
  float2* V0     = (float2*)p;  p += HSLICES * sizeof(float2);               // 8.5 MB
  float2* V1     = (float2*)p;  p += HSLICES * sizeof(float2);               // 8.5 MB
  float2* V2     = (float2*)p;  p += HSLICES * sizeof(float2);               // 8.5 MB
  float4* bkt    = (float4*)p;  p += (size_t)16384 * CAP * 2 * sizeof(float4); // 16.8 MB
  float*  chi    = (float*)p;   p += (size_t)NCELLS * sizeof(float);         // 8.4 MB
  int*    counts = (int*)p;     p += 16384 * sizeof(int);
  float*  sum    = (float*)p;

  hipMemsetAsync(counts, 0, 16384 * sizeof(int) + sizeof(float), stream);  // counts + sum

  scatter_direct<<<(npts + 255) / 256, 256, 0, stream>>>(pts, nrm, counts, bkt, npts);
  fwd_zr<<<1024, 512, 0, stream>>>(bkt, counts, V0, V1, V2);
  fwd_y<<<dim3(520, 3), 512, 0, stream>>>(V0, V1, V2);     // 65 slices x 8 tiles
  pass_xspec<<<dim3(65, 8), 512, 0, stream>>>(V0, V1, V2);
  inv_y<<<520, 512, 0, stream>>>(V0);
  inv_z<<<1024, 512, 0, stream>>>(V0, chi);

  interp_mean<<<(npts + 255) / 256, 256, 0, stream>>>(pts, chi, sum, npts);
  finalize<<<NCELLS / 256, 256, 0, stream>>>(chi, sum, out, npts);
}